// Round 21
// baseline (826.962 us; speedup 1.0000x reference)
//
#include <hip/hip_runtime.h>
#include <hip/hip_bf16.h>

typedef unsigned short u16;
typedef unsigned int u32;
typedef __attribute__((ext_vector_type(4))) float f32x4;
typedef __attribute__((ext_vector_type(8))) short s16x8;

// ---- problem dims ----
static constexpr int Nn = 4, Tt = 16, Hh = 32, Ww = 32, Cc = 256;
static constexpr int Ltok = Nn * Tt * Hh * Ww;   // 65536 tokens

// ---- helpers ----
__device__ __forceinline__ float bf2f(u16 v) {
  union { u32 u; float f; } t; t.u = ((u32)v) << 16; return t.f;
}
__device__ __forceinline__ u16 f2bf(float f) {
  union { u32 u; float f; } t; t.f = f;
  return (u16)((t.u + 0x7fffu + ((t.u >> 16) & 1u)) >> 16);  // RNE
}
__device__ __forceinline__ ushort4 pack4(float a, float b, float c, float d) {
  ushort4 r; r.x = f2bf(a); r.y = f2bf(b); r.z = f2bf(c); r.w = f2bf(d); return r;
}
__device__ __forceinline__ float geluf(float x) {
  return 0.5f * x * (1.0f + erff(x * 0.70710678118654752f));
}
__device__ __forceinline__ float wsum(float v) {
#pragma unroll
  for (int o = 32; o > 0; o >>= 1) v += __shfl_xor(v, o, 64);
  return v;
}
__device__ __forceinline__ void ln_stats(float a0, float a1, float a2, float a3,
                                         float& m, float& inv) {
  float s  = wsum(a0 + a1 + a2 + a3);
  float s2 = wsum(a0 * a0 + a1 * a1 + a2 * a2 + a3 * a3);
  m = s * (1.0f / 256.0f);
  float v = s2 * (1.0f / 256.0f) - m * m;
  inv = rsqrtf(v + 1e-5f);
}
__device__ __forceinline__ void gload16(const u16* g, u16* l) {
  __builtin_amdgcn_global_load_lds(
      (const __attribute__((address_space(1))) void*)g,
      (__attribute__((address_space(3))) void*)l, 16, 0, 0);
}

// ---- positional tables + dwk transpose + zero-bias + QK bias concat ----
__global__ __launch_bounds__(256) void k_pos(float* __restrict__ pe2d,
                                             float* __restrict__ pe1d,
                                             float* __restrict__ dwkT,
                                             float* __restrict__ zb,
                                             float* __restrict__ sqk,
                                             float* __restrict__ tqk,
                                             const float* __restrict__ dwk,
                                             const float* __restrict__ sbq,
                                             const float* __restrict__ sbk,
                                             const float* __restrict__ tbq,
                                             const float* __restrict__ tbk) {
  int idx = blockIdx.x * 256 + threadIdx.x;
  if (idx < 16384) {
    int y = idx >> 11, r = idx & 2047, x = r >> 8, c = r & 255;
    float pos; int cc;
    if (c < 128) { pos = (float)(y + 1); cc = c; }
    else         { pos = (float)(x + 1); cc = c - 128; }
    float e = (float)(cc & ~1) * (1.0f / 128.0f);
    float v = pos / powf(10000.0f, e);
    pe2d[idx] = (cc & 1) ? cosf(v) : sinf(v);
  } else if (idx < 20480) {
    int i = idx - 16384;
    int t = i >> 8, c = i & 255;
    float e = (float)(c & ~1) * (1.0f / 256.0f);
    float v = (float)t * powf(10000.0f, -e);
    pe1d[i] = (c & 1) ? cosf(v) : sinf(v);
  } else if (idx < 29696) {
    int i = idx - 20480;
    int c = i & 1023, tap = i >> 10;
    dwkT[tap * 1024 + c] = dwk[c * 9 + tap];
  } else if (idx < 30720) {
    zb[idx - 29696] = 0.0f;
  } else if (idx < 31232) {
    int i = idx - 30720;
    sqk[i] = (i < 256) ? sbq[i] : sbk[i - 256];
  } else if (idx < 31744) {
    int i = idx - 31232;
    tqk[i] = (i < 256) ? tbq[i] : tbk[i - 256];
  }
}

// ---- weight convert+transpose: dst[N][K] bf16 <- src[K][N] f32 ----
__global__ __launch_bounds__(256) void k_wprep(
    const float* __restrict__ s0, const float* __restrict__ s1,
    const float* __restrict__ s2, const float* __restrict__ s3,
    const float* __restrict__ s4, const float* __restrict__ s5,
    const float* __restrict__ s6, const float* __restrict__ s7,
    const float* __restrict__ cW1, const float* __restrict__ cW2,
    const float* __restrict__ fW1, const float* __restrict__ fW2,
    u16* __restrict__ WT) {
  __shared__ float Ls[32][33];
  int b = blockIdx.x;
  const float* src; u16* dst; int Kd, Nd, tb;
  if (b < 512) {
    int seg = b >> 6; tb = b & 63; Kd = 256; Nd = 256;
    const float* tab[8] = {s0, s1, s2, s3, s4, s5, s6, s7};
    src = tab[seg]; dst = WT + seg * 65536;
  } else if (b < 768)  { tb = b - 512;  Kd = 256;  Nd = 1024; src = cW1; dst = WT + 524288; }
  else if (b < 1024)   { tb = b - 768;  Kd = 1024; Nd = 256;  src = cW2; dst = WT + 786432; }
  else if (b < 1280)   { tb = b - 1024; Kd = 256;  Nd = 1024; src = fW1; dst = WT + 1048576; }
  else                 { tb = b - 1280; Kd = 1024; Nd = 256;  src = fW2; dst = WT + 1310720; }
  int nt = Nd >> 5;
  int tk = tb / nt, tn = tb % nt;
  int r = threadIdx.x >> 3, c0 = (threadIdx.x & 7) * 4;
  float4 v = *(const float4*)&src[(size_t)(tk * 32 + r) * Nd + tn * 32 + c0];
  Ls[r][c0] = v.x; Ls[r][c0 + 1] = v.y; Ls[r][c0 + 2] = v.z; Ls[r][c0 + 3] = v.w;
  __syncthreads();
  *(ushort4*)&dst[(size_t)(tn * 32 + r) * Kd + tk * 32 + c0] =
      pack4(Ls[c0][r], Ls[c0 + 1][r], Ls[c0 + 2][r], Ls[c0 + 3][r]);
}

// ---- LN kernels ----
__global__ __launch_bounds__(256) void k_ln1(const float* __restrict__ x,
                                             const float* __restrict__ g,
                                             const float* __restrict__ b,
                                             const float* __restrict__ pe2d,
                                             u16* __restrict__ qk,
                                             u16* __restrict__ vv) {
  int l = blockIdx.x * 4 + (threadIdx.x >> 6);
  int lane = threadIdx.x & 63, c0 = lane * 4;
  int idx = l & 1023, hh = idx >> 5, ww = idx & 31;
  float4 xv = *(const float4*)&x[(size_t)l * Cc + c0];
  float4 pv = *(const float4*)&pe2d[(((hh & 7) << 3) | (ww & 7)) * Cc + c0];
  float q0 = xv.x + pv.x, q1 = xv.y + pv.y, q2 = xv.z + pv.z, q3 = xv.w + pv.w;
  float mx, ix, mq, iq;
  ln_stats(xv.x, xv.y, xv.z, xv.w, mx, ix);
  ln_stats(q0, q1, q2, q3, mq, iq);
  float4 gv = *(const float4*)&g[c0];
  float4 bv = *(const float4*)&b[c0];
  *(ushort4*)&qk[(size_t)l * Cc + c0] =
      pack4((q0 - mq) * iq * gv.x + bv.x, (q1 - mq) * iq * gv.y + bv.y,
            (q2 - mq) * iq * gv.z + bv.z, (q3 - mq) * iq * gv.w + bv.w);
  *(ushort4*)&vv[(size_t)l * Cc + c0] =
      pack4((xv.x - mx) * ix * gv.x + bv.x, (xv.y - mx) * ix * gv.y + bv.y,
            (xv.z - mx) * ix * gv.z + bv.z, (xv.w - mx) * ix * gv.w + bv.w);
}

// bf16-input LN
__global__ __launch_bounds__(256) void k_lnb(const u16* __restrict__ x,
                                             const float* __restrict__ g,
                                             const float* __restrict__ b,
                                             u16* __restrict__ out) {
  int l = blockIdx.x * 4 + (threadIdx.x >> 6);
  int lane = threadIdx.x & 63, c0 = lane * 4;
  ushort4 xv4 = *(const ushort4*)&x[(size_t)l * Cc + c0];
  float x0 = bf2f(xv4.x), x1 = bf2f(xv4.y), x2 = bf2f(xv4.z), x3 = bf2f(xv4.w);
  float m, inv;
  ln_stats(x0, x1, x2, x3, m, inv);
  float4 gv = *(const float4*)&g[c0];
  float4 bv = *(const float4*)&b[c0];
  *(ushort4*)&out[(size_t)l * Cc + c0] =
      pack4((x0 - m) * inv * gv.x + bv.x, (x1 - m) * inv * gv.y + bv.y,
            (x2 - m) * inv * gv.z + bv.z, (x3 - m) * inv * gv.w + bv.w);
}

// LN3 stage, bf16 input
__global__ __launch_bounds__(256) void k_ln3b(const u16* __restrict__ xa,
                                              const float* __restrict__ g,
                                              const float* __restrict__ b,
                                              const float* __restrict__ pe1d,
                                              u16* __restrict__ xt_base,
                                              u16* __restrict__ qt,
                                              u16* __restrict__ vt) {
  int l = blockIdx.x * 4 + (threadIdx.x >> 6);
  int lane = threadIdx.x & 63, c0 = lane * 4;
  ushort4 xv4 = *(const ushort4*)&xa[(size_t)l * Cc + c0];
  float x0 = bf2f(xv4.x), x1 = bf2f(xv4.y), x2 = bf2f(xv4.z), x3 = bf2f(xv4.w);
  float4 gv = *(const float4*)&g[c0];
  float4 bv = *(const float4*)&b[c0];
  float m, inv;
  ln_stats(x0, x1, x2, x3, m, inv);
  float t0 = (x0 - m) * inv * gv.x + bv.x;
  float t1 = (x1 - m) * inv * gv.y + bv.y;
  float t2 = (x2 - m) * inv * gv.z + bv.z;
  float t3 = (x3 - m) * inv * gv.w + bv.w;
  *(ushort4*)&xt_base[(size_t)l * Cc + c0] = pack4(t0, t1, t2, t3);
  float m2, inv2;
  ln_stats(t0, t1, t2, t3, m2, inv2);
  *(ushort4*)&vt[(size_t)l * Cc + c0] =
      pack4((t0 - m2) * inv2 * gv.x + bv.x, (t1 - m2) * inv2 * gv.y + bv.y,
            (t2 - m2) * inv2 * gv.z + bv.z, (t3 - m2) * inv2 * gv.w + bv.w);
  int tt = (l >> 10) & 15;
  float4 pv = *(const float4*)&pe1d[tt * Cc + c0];
  float s0 = t0 + pv.x, s1 = t1 + pv.y, s2 = t2 + pv.z, s3 = t3 + pv.w;
  float m3, inv3;
  ln_stats(s0, s1, s2, s3, m3, inv3);
  *(ushort4*)&qt[(size_t)l * Cc + c0] =
      pack4((s0 - m3) * inv3 * gv.x + bv.x, (s1 - m3) * inv3 * gv.y + bv.y,
            (s2 - m3) * inv3 * gv.z + bv.z, (s3 - m3) * inv3 * gv.w + bv.w);
}

// ---- STREAMING GEMM (tall-skinny), multi-split: grid (splits, 512).
// per-x offsets: WT += bx*wt_stride, bias += bx*bias_stride, out += bx*out_xoff.
// MODE 0: ->bf16 ; 1: gelu->bf16 ; 3: +res(bf16)->bf16 ; 5: ->bf16 transposed
// (coalesced) ; 7: +res(f32)->bf16.
template <int MODE>
__global__ __launch_bounds__(256, 2) void k_sgemm(const u16* __restrict__ A,
                                                  const u16* __restrict__ WT,
                                                  int wt_stride,
                                                  const float* __restrict__ bias,
                                                  int bias_stride,
                                                  const void* __restrict__ res,
                                                  void* __restrict__ out,
                                                  size_t out_xoff, int ldout) {
  __shared__ u16 SMEM[32768];        // A dbuf 2x16KB + scratch 32KB = 64KB
  const int tid = threadIdx.x;
  const int wave = tid >> 6, lane = tid & 63;
  const int fr = lane & 15, fs = lane >> 4;
  const int bx = blockIdx.x;
  const int r0base = blockIdx.y * 128;
  WT += (size_t)bx * wt_stride;
  bias += bx * bias_stride;
  u16* ob = (u16*)out + (size_t)bx * out_xoff;
  s16x8 wreg[4][8];
#pragma unroll
  for (int ni = 0; ni < 4; ++ni)
#pragma unroll
    for (int kt = 0; kt < 8; ++kt)
      wreg[ni][kt] = *(const s16x8*)&WT[(size_t)(wave * 64 + ni * 16 + fr) * 256 +
                                        kt * 32 + fs * 8];
  auto stage = [&](int buf, int r0) {
    u16* Ad = SMEM + buf * 8192;
#pragma unroll
    for (int i = 0; i < 4; ++i) {
      int idx = i * 256 + tid;
      int row = idx >> 5, s = idx & 31;
      gload16(A + (size_t)(r0 + row) * 256 + ((s ^ row) << 3), &Ad[idx * 8]);
    }
  };
  float* sc = (float*)(SMEM + 16384) + wave * 2048;   // per-wave 32x64 f32
  u16* sc2 = SMEM + 16384 + wave * 2048;              // per-wave 64x32 bf16 (MODE 5)
  stage(0, r0base);
  __syncthreads();
#pragma unroll 1
  for (int c = 0; c < 4; ++c) {
    if (c < 3) stage((c + 1) & 1, r0base + (c + 1) * 32);
    const u16* As = SMEM + (c & 1) * 8192;
    f32x4 acc[2][4] = {};
#pragma unroll
    for (int kt = 0; kt < 8; ++kt) {
      s16x8 a0 = *(const s16x8*)&As[(fr * 32 + ((kt * 4 + fs) ^ fr)) * 8];
      s16x8 a1 = *(const s16x8*)&As[((16 + fr) * 32 + ((kt * 4 + fs) ^ (16 + fr))) * 8];
#pragma unroll
      for (int ni = 0; ni < 4; ++ni) {
        acc[0][ni] = __builtin_amdgcn_mfma_f32_16x16x32_bf16(a0, wreg[ni][kt],
                                                             acc[0][ni], 0, 0, 0);
        acc[1][ni] = __builtin_amdgcn_mfma_f32_16x16x32_bf16(a1, wreg[ni][kt],
                                                             acc[1][ni], 0, 0, 0);
      }
    }
    const int r0 = r0base + c * 32;
    if constexpr (MODE == 5) {
      u16* o = (u16*)out;
#pragma unroll
      for (int ni = 0; ni < 4; ++ni) {
        float bv = bias[wave * 64 + ni * 16 + fr];
#pragma unroll
        for (int mi = 0; mi < 2; ++mi)
#pragma unroll
          for (int r = 0; r < 4; ++r) {
            int row = mi * 16 + fs * 4 + r;
            int col = ni * 16 + fr;
            sc2[col * 32 + row] = f2bf(acc[mi][ni][r] + bv);
          }
      }
#pragma unroll
      for (int p = 0; p < 4; ++p) {
        int gcl = p * 16 + (lane >> 2);
        int sub = lane & 3;
        uint4 u = *(const uint4*)&sc2[gcl * 32 + sub * 8];
        int gc = wave * 64 + gcl;
        *(uint4*)&o[(size_t)gc * (size_t)Ltok + r0 + sub * 8] = u;
      }
    } else {
#pragma unroll
      for (int mi = 0; mi < 2; ++mi)
#pragma unroll
        for (int ni = 0; ni < 4; ++ni)
#pragma unroll
          for (int r = 0; r < 4; ++r) {
            int row = mi * 16 + fs * 4 + r;
            int col = ni * 16 + fr;
            sc[row * 64 + (col ^ ((row & 7) << 3))] = acc[mi][ni][r];
          }
#pragma unroll
      for (int p = 0; p < 8; ++p) {
        int row = p * 4 + (lane >> 4);
        int c4 = (lane & 15) * 4;
        f32x4 v4 = *(const f32x4*)&sc[row * 64 + (c4 ^ ((row & 7) << 3))];
        int gr = r0 + row;
        int gc = wave * 64 + c4;
        float4 bv4 = *(const float4*)&bias[gc];
        float v[4] = {v4[0] + bv4.x, v4[1] + bv4.y, v4[2] + bv4.z, v4[3] + bv4.w};
        size_t o = (size_t)gr * (size_t)ldout + gc;
        if constexpr (MODE == 1) {
#pragma unroll
          for (int j = 0; j < 4; ++j) v[j] = geluf(v[j]);
        }
        if constexpr (MODE == 3) {
          ushort4 r4 = *(const ushort4*)&((const u16*)res)[(size_t)gr * 256 + gc];
          v[0] += bf2f(r4.x); v[1] += bf2f(r4.y); v[2] += bf2f(r4.z); v[3] += bf2f(r4.w);
        }
        if constexpr (MODE == 7) {
          float4 r4 = *(const float4*)&((const float*)res)[(size_t)gr * 256 + gc];
          v[0] += r4.x; v[1] += r4.y; v[2] += r4.z; v[3] += r4.w;
        }
        *(ushort4*)&ob[o] = pack4(v[0], v[1], v[2], v[3]);
      }
    }
    __syncthreads();
  }
}

// ---- k_m2: 2-phase dbuf GEMM, BM=128 x BN=128, BK=32 (conv2, K=512) ----
template <int MODE>
__global__ __launch_bounds__(256, 2) void k_m2(const u16* __restrict__ A,
                                               const u16* __restrict__ BT, int ldbt,
                                               const float* __restrict__ bias,
                                               const void* __restrict__ res,
                                               void* __restrict__ out, int K) {
  __shared__ u16 SMEM[16384];
  const int tid = threadIdx.x;
  const int wave = tid >> 6, lane = tid & 63;
  const int fr = lane & 15, fs = lane >> 4;
  const int bid = blockIdx.x;
  const int m0 = (bid >> 1) * 128, n0 = (bid & 1) * 128;
  const int wm = wave >> 1, wn = wave & 1;
  f32x4 acc[4][4] = {};

  auto stage = [&](int buf, int k0) {
    u16* Ad = SMEM + buf * 8192;
    u16* Bd = Ad + 4096;
#pragma unroll
    for (int i = 0; i < 2; ++i) {
      int idx = i * 256 + tid;
      int row = idx >> 2, s = idx & 3;
      gload16(A + (size_t)(m0 + row) * K + k0 + ((s ^ (row & 3)) << 3), &Ad[idx * 8]);
      gload16(BT + (size_t)(n0 + row) * ldbt + k0 + ((s ^ (row & 3)) << 3),
              &Bd[idx * 8]);
    }
  };
  auto compute = [&](int buf) {
    const u16* As = SMEM + buf * 8192;
    const u16* Bs = As + 4096;
    s16x8 af[4], bfr[4];
#pragma unroll
    for (int i = 0; i < 4; ++i) {
      int ra = wm * 64 + i * 16 + fr;
      af[i] = *(const s16x8*)&As[ra * 32 + ((fs ^ (ra & 3)) << 3)];
      int rb = wn * 64 + i * 16 + fr;
      bfr[i] = *(const s16x8*)&Bs[rb * 32 + ((fs ^ (rb & 3)) << 3)];
    }
#pragma unroll
    for (int mi = 0; mi < 4; ++mi)
#pragma unroll
      for (int ni = 0; ni < 4; ++ni)
        acc[mi][ni] = __builtin_amdgcn_mfma_f32_16x16x32_bf16(af[mi], bfr[ni],
                                                              acc[mi][ni], 0, 0, 0);
  };

  stage(0, 0);
  __syncthreads();
  const int nt = K >> 5;
  int cur = 0;
  for (int t = 0; t < nt; ++t) {
    if (t < nt - 1) stage(cur ^ 1, (t + 1) << 5);
    compute(cur);
    __syncthreads();
    cur ^= 1;
  }
  float* Wl = (float*)SMEM + wave * 2048;
#pragma unroll
  for (int nh = 0; nh < 2; ++nh) {
#pragma unroll
    for (int mi = 0; mi < 4; ++mi)
#pragma unroll
      for (int nq = 0; nq < 2; ++nq) {
        int ni = nh * 2 + nq;
#pragma unroll
        for (int r = 0; r < 4; ++r) {
          int row = mi * 16 + fs * 4 + r;
          int col = nq * 16 + fr;
          Wl[row * 32 + (col ^ ((row & 7) << 2))] = acc[mi][ni][r];
        }
      }
#pragma unroll
    for (int p = 0; p < 8; ++p) {
      int row = p * 8 + (lane >> 3);
      int c4 = (lane & 7) * 4;
      f32x4 v4 = *(const f32x4*)&Wl[row * 32 + (c4 ^ ((row & 7) << 2))];
      int gr = m0 + wm * 64 + row;
      int gc = n0 + wn * 64 + nh * 32 + c4;
      float4 bv4 = *(const float4*)&bias[gc];
      float v[4] = {v4[0] + bv4.x, v4[1] + bv4.y, v4[2] + bv4.z, v4[3] + bv4.w};
      size_t o = (size_t)gr * 256 + gc;
      ushort4 r4 = *(const ushort4*)&((const u16*)res)[o];
      v[0] += bf2f(r4.x); v[1] += bf2f(r4.y); v[2] += bf2f(r4.z); v[3] += bf2f(r4.w);
      *(ushort4*)&((u16*)out)[o] = pack4(v[0], v[1], v[2], v[3]);
    }
    __syncthreads();
  }
}

// ---- FUSED LN4+FFN v6: out[L,256](f32) = 2*(gelu(LN(xt)@W1+b1)@W2+b2)
// 64-row blocks (grid 1024); xt staged once (32KB), LN applied IN LDS;
// 16 hidden-slices of 64 with single H buffer (8KB). LDS 40KB -> 4 blocks/CU.
__global__ __launch_bounds__(256, 4) void k_ffn(const u16* __restrict__ X,
                                                const float* __restrict__ g4,
                                                const float* __restrict__ b4,
                                                const u16* __restrict__ W1T,
                                                const float* __restrict__ fb1,
                                                const u16* __restrict__ W2T,
                                                const float* __restrict__ fb2,
                                                float* __restrict__ out) {
  __shared__ u16 SMEM[20480];   // A [64][256] 32KB + H [64][64] 8KB = 40KB
  const int tid = threadIdx.x;
  const int wave = tid >> 6, lane = tid & 63;
  const int fr = lane & 15, fs = lane >> 4;
  const int r0 = blockIdx.x * 64;
  u16* Ald = SMEM;
  u16* Hld = SMEM + 16384;
#pragma unroll
  for (int i = 0; i < 8; ++i) {
    int idx = i * 256 + tid;
    int row = idx >> 5, s = idx & 31;
    gload16(X + (size_t)(r0 + row) * 256 + ((s ^ (row & 7)) << 3), &Ald[idx * 8]);
  }
  __syncthreads();
  // ---- fused LN4 in LDS: thread owns 1/4 row (8 swizzled 16B slots) ----
  {
    const int row = tid >> 2, part = tid & 3;
    float sum = 0.f, sq = 0.f;
#pragma unroll
    for (int s = 0; s < 8; ++s) {
      int slot = part * 8 + s;
      s16x8 v = *(const s16x8*)&Ald[row * 256 + ((slot ^ (row & 7)) << 3)];
#pragma unroll
      for (int j = 0; j < 8; ++j) {
        float f = bf2f((u16)v[j]);
        sum += f; sq += f * f;
      }
    }
    sum += __shfl_xor(sum, 1, 64); sum += __shfl_xor(sum, 2, 64);
    sq  += __shfl_xor(sq, 1, 64);  sq  += __shfl_xor(sq, 2, 64);
    float m = sum * (1.0f / 256.0f);
    float inv = rsqrtf(sq * (1.0f / 256.0f) - m * m + 1e-5f);
#pragma unroll
    for (int s = 0; s < 8; ++s) {
      int slot = part * 8 + s;
      u16* p = &Ald[row * 256 + ((slot ^ (row & 7)) << 3)];
      s16x8 v = *(const s16x8*)p;
      int c0 = slot * 8;
      float4 ga = *(const float4*)&g4[c0];
      float4 gb = *(const float4*)&g4[c0 + 4];
      float4 ba = *(const float4*)&b4[c0];
      float4 bb = *(const float4*)&b4[c0 + 4];
      u16 ov[8];
      ov[0] = f2bf((bf2f((u16)v[0]) - m) * inv * ga.x + ba.x);
      ov[1] = f2bf((bf2f((u16)v[1]) - m) * inv * ga.y + ba.y);
      ov[2] = f2bf((bf2f((u16)v[2]) - m) * inv * ga.z + ba.z);
      ov[3] = f2bf((bf2f((u16)v[3]) - m) * inv * ga.w + ba.w);
      ov[4] = f2bf((bf2f((u16)v[4]) - m) * inv * gb.x + bb.x);
      ov[5] = f2bf((bf2f((u16)v[5]) - m) * inv * gb.y + bb.y);
      ov[6] = f2bf((bf2f((u16)v[6]) - m) * inv * gb.z + bb.z);
      ov[7] = f2bf((bf2f((u16)v[7]) - m) * inv * gb.w + bb.w);
      *(uint4*)p = *(const uint4*)ov;
    }
  }
  __syncthreads();
  f32x4 acc[4][4] = {};
#pragma unroll 1
  for (int j = 0; j < 16; ++j) {
    s16x8 w1f[8];
#pragma unroll
    for (int kt = 0; kt < 8; ++kt)
      w1f[kt] = *(const s16x8*)&W1T[(size_t)(j * 64 + wave * 16 + fr) * 256 +
                                    kt * 32 + fs * 8];
    f32x4 h[4] = {};
#pragma unroll
    for (int kt = 0; kt < 8; ++kt)
#pragma unroll
      for (int mi = 0; mi < 4; ++mi) {
        int row = mi * 16 + fr;
        s16x8 a = *(const s16x8*)&Ald[row * 256 + (((kt * 4 + fs) ^ (row & 7)) << 3)];
        h[mi] = __builtin_amdgcn_mfma_f32_16x16x32_bf16(w1f[kt], a, h[mi], 0, 0, 0);
      }
    float4 b1 = *(const float4*)&fb1[j * 64 + wave * 16 + fs * 4];
    s16x8 w2f[2][4];
#pragma unroll
    for (int kk = 0; kk < 2; ++kk)
#pragma unroll
      for (int nj = 0; nj < 4; ++nj)
        w2f[kk][nj] = *(const s16x8*)&W2T[(size_t)(wave * 64 + nj * 16 + fr) * 1024 +
                                          j * 64 + kk * 32 + fs * 8];
    __syncthreads();   // prev slice's PV reads of Hld are done
#pragma unroll
    for (int mi = 0; mi < 4; ++mi) {
      int tk = mi * 16 + fr;
      int slot = (wave * 2 + (fs >> 1)) ^ (tk & 7);
      *(ushort4*)((char*)Hld + tk * 128 + slot * 16 + (fs & 1) * 8) =
          pack4(geluf(h[mi][0] + b1.x), geluf(h[mi][1] + b1.y),
                geluf(h[mi][2] + b1.z), geluf(h[mi][3] + b1.w));
    }
    __syncthreads();   // H ready
#pragma unroll
    for (int kk = 0; kk < 2; ++kk) {
      s16x8 ha[4];
#pragma unroll
      for (int mi = 0; mi < 4; ++mi) {
        int row = mi * 16 + fr;
        ha[mi] = *(const s16x8*)&Hld[row * 64 + (((kk * 4 + fs) ^ (row & 7)) << 3)];
      }
#pragma unroll
      for (int mi = 0; mi < 4; ++mi)
#pragma unroll
        for (int nj = 0; nj < 4; ++nj)
          acc[mi][nj] = __builtin_amdgcn_mfma_f32_16x16x32_bf16(ha[mi], w2f[kk][nj],
                                                                acc[mi][nj], 0, 0, 0);
    }
  }
  float* Wl = (float*)Ald + wave * 2048;
#pragma unroll
  for (int nh = 0; nh < 2; ++nh) {
#pragma unroll
    for (int mi = 0; mi < 4; ++mi)
#pragma unroll
      for (int nq = 0; nq < 2; ++nq) {
        int ni = nh * 2 + nq;
#pragma unroll
        for (int r = 0; r < 4; ++r) {
          int row = mi * 16 + fs * 4 + r;
          int col = nq * 16 + fr;
          Wl[row * 32 + (col ^ ((row & 7) << 2))] = acc[mi][ni][r];
        }
      }
#pragma unroll
    for (int p = 0; p < 8; ++p) {
      int row = p * 8 + (lane >> 3);
      int c4 = (lane & 7) * 4;
      f32x4 v4 = *(const f32x4*)&Wl[row * 32 + (c4 ^ ((row & 7) << 2))];
      int gr = r0 + row;
      int gc = wave * 64 + nh * 32 + c4;
      float4 bv4 = *(const float4*)&fb2[gc];
      *(float4*)&out[(size_t)gr * 256 + gc] =
          make_float4((v4[0] + bv4.x) * 2.0f, (v4[1] + bv4.y) * 2.0f,
                      (v4[2] + bv4.z) * 2.0f, (v4[3] + bv4.w) * 2.0f);
    }
  }
}

// ---- spatial windowed attention ----
__global__ __launch_bounds__(256) void k_sattn2(const u16* __restrict__ Q,
                                                const u16* __restrict__ Kb,
                                                const u16* __restrict__ VT,
                                                u16* __restrict__ ctx) {
  __shared__ u16 P_lds[4][4096];
  const int tid = threadIdx.x;
  const int wave = tid >> 6, lane = tid & 63;
  const int fr = lane & 15, fs = lane >> 4;
  const int wi = blockIdx.x >> 1;
  const int head = (blockIdx.x & 1) * 4 + wave;
  const int ft = wi >> 4, wy = (wi >> 2) & 3, wx = wi & 3;
  const int base = ft * 1024 + wy * 256 + wx * 8;
  const float scale = 0.17677669529663688f;
  const int ch = head * 32 + fs * 8;
  s16x8 ka[4], qb[4];
#pragma unroll
  for (int t4 = 0; t4 < 4; ++t4) {
    int tok = base + (2 * t4 + (fr >> 3)) * 32 + (fr & 7);
    ka[t4] = *(const s16x8*)&Kb[(size_t)tok * 256 + ch];
    qb[t4] = *(const s16x8*)&Q[(size_t)tok * 256 + ch];
  }
  f32x4 s[4][4] = {};
#pragma unroll
  for (int kt = 0; kt < 4; ++kt)
#pragma unroll
    for (int qt = 0; qt < 4; ++qt)
      s[kt][qt] = __builtin_amdgcn_mfma_f32_16x16x32_bf16(ka[kt], qb[qt], s[kt][qt], 0, 0, 0);
  u16* pw = P_lds[wave];
#pragma unroll
  for (int qt = 0; qt < 4; ++qt) {
    float m = -1e30f;
#pragma unroll
    for (int kt = 0; kt < 4; ++kt)
#pragma unroll
      for (int r = 0; r < 4; ++r) m = fmaxf(m, s[kt][qt][r]);
    m = fmaxf(m, __shfl_xor(m, 16, 64));
    m = fmaxf(m, __shfl_xor(m, 32, 64));
    m *= scale;
    float e[4][4];
    float sum = 0.f;
#pragma unroll
    for (int kt = 0; kt < 4; ++kt)
#pragma unroll
      for (int r = 0; r < 4; ++r) {
        e[kt][r] = __expf(s[kt][qt][r] * scale - m);
        sum += e[kt][r];
      }
    sum += __shfl_xor(sum, 16, 64);
    sum += __shfl_xor(sum, 32, 64);
    float il = 1.0f / sum;
    int q = qt * 16 + fr;
    int rowb = q * 128, sw = (q & 7) << 4;
#pragma unroll
    for (int kt = 0; kt < 4; ++kt)
      *(ushort4*)((char*)pw + ((rowb + kt * 32 + fs * 8) ^ sw)) =
          pack4(e[kt][0] * il, e[kt][1] * il, e[kt][2] * il, e[kt][3] * il);
  }
  f32x4 o[4][2] = {};
#pragma unroll
  for (int ks = 0; ks < 2; ++ks) {
    s16x8 vb[2];
#pragma unroll
    for (int nt = 0; nt < 2; ++nt) {
      int d = head * 32 + nt * 16 + fr;
      int tok = base + (ks * 4 + fs) * 32;
      vb[nt] = *(const s16x8*)&VT[(size_t)d * (size_t)Ltok + tok];
    }
#pragma unroll
    for (int qt = 0; qt < 4; ++qt) {
      int q = qt * 16 + fr;
      s16x8 pa = *(const s16x8*)((char*)pw +
                                 ((q * 128 + ks * 64 + fs * 16) ^ ((q & 7) << 4)));
#pragma unroll
      for (int nt = 0; nt < 2; ++nt)
        o[qt][nt] = __builtin_amdgcn_mfma_f32_16x16x32_bf16(pa, vb[nt], o[qt][nt], 0, 0, 0);
    }
  }
#pragma unroll
  for (int qt = 0; qt < 4; ++qt)
#pragma unroll
    for (int r = 0; r < 4; ++r) {
      int q = qt * 16 + fs * 4 + r;
      int tok = base + (q >> 3) * 32 + (q & 7);
#pragma unroll
      for (int nt = 0; nt < 2; ++nt)
        ctx[(size_t)tok * 256 + head * 32 + nt * 16 + fr] = f2bf(o[qt][nt][r]);
    }
}

// ---- temporal attention ----
__global__ __launch_bounds__(256) void k_tattn2(const u16* __restrict__ Q,
                                                const u16* __restrict__ Kb,
                                                const u16* __restrict__ V,
                                                u16* __restrict__ ctx) {
  __shared__ u16 Vs[16 * 256];
  const int tid = threadIdx.x;
  const int b = blockIdx.x;
  const int n = b >> 10, hw = b & 1023;
  const int tok0 = n * 16384 + hw;
#pragma unroll
  for (int i = 0; i < 2; ++i) {
    int chunk = tid * 2 + i;
    int row = chunk >> 5, c8 = (chunk & 31) * 8;
    *(uint4*)&Vs[row * 256 + c8] =
        *(const uint4*)&V[(size_t)(tok0 + row * 1024) * 256 + c8];
  }
  __syncthreads();
  const int wave = tid >> 6, lane = tid & 63;
  const int fr = lane & 15, fs = lane >> 4;
  const float scale = 0.17677669529663688f;
#pragma unroll
  for (int hg = 0; hg < 2; ++hg) {
    int head = wave + hg * 4;
    int ch = head * 32 + fs * 8;
    size_t go = (size_t)(tok0 + fr * 1024) * 256 + ch;
    s16x8 ka = *(const s16x8*)&Kb[go];
    s16x8 qb = *(const s16x8*)&Q[go];
    f32x4 s = {0.f, 0.f, 0.f, 0.f};
    s = __builtin_amdgcn_mfma_f32_16x16x32_bf16(ka, qb, s, 0, 0, 0);
    float m = fmaxf(fmaxf(s[0], s[1]), fmaxf(s[2], s[3]));
    m = fmaxf(m, __shfl_xor(m, 16, 64));
    m = fmaxf(m, __shfl_xor(m, 32, 64));
    m *= scale;
    float e0 = __expf(s[0] * scale - m), e1 = __expf(s[1] * scale - m);
    float e2 = __expf(s[2] * scale - m), e3 = __expf(s[3] * scale - m);
    float sum = e0 + e1 + e2 + e3;
    sum += __shfl_xor(sum, 16, 64);
    sum += __shfl_xor(sum, 32, 64);
    float il = 1.0f / sum;
    e0 *= il; e1 *= il; e2 *= il; e3 *= il;
    float o[8] = {};
#pragma unroll
    for (int kb = 0; kb < 4; ++kb) {
      int src = kb * 16 + fr;
      float p0 = __shfl(e0, src, 64);
      float p1 = __shfl(e1, src, 64);
      float p2 = __shfl(e2, src, 64);
      float p3 = __shfl(e3, src, 64);
#pragma unroll
      for (int r = 0; r < 4; ++r) {
        float p = r == 0 ? p0 : (r == 1 ? p1 : (r == 2 ? p2 : p3));
        uint4 vv = *(const uint4*)&Vs[(kb * 4 + r) * 256 + ch];
        const u16* vp = (const u16*)&vv;
#pragma unroll
        for (int u = 0; u < 8; ++u) o[u] = fmaf(p, bf2f(vp[u]), o[u]);
      }
    }
    size_t co = (size_t)(tok0 + fr * 1024) * 256 + ch;
    *(ushort4*)&ctx[co] = pack4(o[0], o[1], o[2], o[3]);
    *(ushort4*)&ctx[co + 4] = pack4(o[4], o[5], o[6], o[7]);
  }
}

// ---- depthwise 3x3 conv + bias + GELU on a 256-channel quarter, out stride 512 ----
__global__ __launch_bounds__(256) void k_dwconv(const u16* __restrict__ Hin,
                                                const float* __restrict__ dwkT,
                                                const float* __restrict__ dwb,
                                                int ch0, int oco,
                                                u16* __restrict__ Hout) {
  int flat = blockIdx.x * 256 + threadIdx.x;
  int l = flat >> 5, cg = flat & 31, c0 = cg * 8, tc0 = ch0 + c0;
  int frame = l >> 10, idx = l & 1023, hh = idx >> 5, ww = idx & 31;
  float acc[8];
  *(float4*)&acc[0] = *(const float4*)&dwb[tc0];
  *(float4*)&acc[4] = *(const float4*)&dwb[tc0 + 4];
#pragma unroll
  for (int ky = -1; ky <= 1; ++ky) {
    int h2 = hh + ky;
    if (h2 < 0 || h2 >= 32) continue;
#pragma unroll
    for (int kx = -1; kx <= 1; ++kx) {
      int w2 = ww + kx;
      if (w2 < 0 || w2 >= 32) continue;
      int ln = frame * 1024 + h2 * 32 + w2;
      uint4 hv = *(const uint4*)&Hin[(size_t)ln * 256 + c0];
      const u16* hp = (const u16*)&hv;
      int tap = (ky + 1) * 3 + (kx + 1);
      float wk[8];
      *(float4*)&wk[0] = *(const float4*)&dwkT[tap * 1024 + tc0];
      *(float4*)&wk[4] = *(const float4*)&dwkT[tap * 1024 + tc0 + 4];
#pragma unroll
      for (int u = 0; u < 8; ++u) acc[u] = fmaf(bf2f(hp[u]), wk[u], acc[u]);
    }
  }
  size_t ob = (size_t)l * 512 + oco + c0;
  *(ushort4*)&Hout[ob] = pack4(geluf(acc[0]), geluf(acc[1]), geluf(acc[2]), geluf(acc[3]));
  *(ushort4*)&Hout[ob + 4] = pack4(geluf(acc[4]), geluf(acc[5]), geluf(acc[6]), geluf(acc[7]));
}

extern "C" void kernel_launch(void* const* d_in, const int* in_sizes, int n_in,
                              void* d_out, int out_size, void* d_ws, size_t ws_size,
                              hipStream_t stream) {
  (void)in_sizes; (void)n_in; (void)out_size; (void)ws_size;
  const float* x   = (const float*)d_in[0];
  const float* g1  = (const float*)d_in[1];  const float* b1  = (const float*)d_in[2];
  const float* g2  = (const float*)d_in[3];  const float* b2  = (const float*)d_in[4];
  const float* g3  = (const float*)d_in[5];  const float* b3  = (const float*)d_in[6];
  const float* g4  = (const float*)d_in[7];  const float* b4  = (const float*)d_in[8];
  const float* sWq = (const float*)d_in[9];  const float* sbq = (const float*)d_in[10];
  const float* sWk = (const float*)d_in[11]; const float* sbk = (const float*)d_in[12];
  const float* sWv = (const float*)d_in[13]; const float* sbv = (const float*)d_in[14];
  const float* sWo = (const float*)d_in[15]; const float* sbo = (const float*)d_in[16];
  const float* tWq = (const float*)d_in[17]; const float* tbq = (const float*)d_in[18];
  const float* tWk = (const float*)d_in[19]; const float* tbk = (const float*)d_in[20];
  const float* tWv = (const float*)d_in[21]; const float* tbv = (const float*)d_in[22];
  const float* tWo = (const float*)d_in[23]; const float* tbo = (const float*)d_in[24];
  const float* cW1 = (const float*)d_in[25]; const float* cb1 = (const float*)d_in[26];
  const float* dwk = (const float*)d_in[27]; const float* dwb = (const float*)d_in[28];
  const float* cW2 = (const float*)d_in[29]; const float* cb2 = (const float*)d_in[30];
  const float* fW1 = (const float*)d_in[31]; const float* fb1 = (const float*)d_in[32];
  const float* fW2 = (const float*)d_in[33]; const float* fb2 = (const float*)d_in[34];

  char* ws = (char*)d_ws;
  const size_t MB = 1ull << 20;
  float* PE2D = (float*)(ws);
  float* PE1D = (float*)(ws + (64 << 10));
  float* DWKT = (float*)(ws + (80 << 10));
  float* ZB   = (float*)(ws + (116 << 10));
  float* SQK  = (float*)(ws + (120 << 10));
  float* TQK  = (float*)(ws + (122 << 10));
  u16*   WT   = (u16*)(ws + (128 << 10));
  u16* XA  = (u16*)(ws + 4 * MB);     // bf16 residual [L,256]
  u16* X1  = (u16*)(ws + 4 * MB);     // temporal Q (XA dead by then)
  u16* B1  = (u16*)(ws + 68 * MB);
  u16* B2  = (u16*)(ws + 100 * MB);
  u16* B3  = (u16*)(ws + 132 * MB);
  u16* B4  = (u16*)(ws + 164 * MB);   // peak 196 MB
  u16* H2h = B3;                      // [L,512] conv hidden half

  u16* sWqT = WT;               // +65536 = sWkT (contiguous)
  u16* sWvT = WT + 2 * 65536;   u16* sWoT = WT + 3 * 65536;
  u16* tWqT = WT + 4 * 65536;   // +65536 = tWkT
  u16* tWvT = WT + 6 * 65536;   u16* tWoT = WT + 7 * 65536;
  u16* cW1T = WT + 524288;      u16* cW2T = WT + 786432;
  u16* fW1T = WT + 1048576;     u16* fW2T = WT + 1310720;

  dim3 blk(256);
  dim3 gLN(Ltok / 4);
  dim3 gM2(1024);

  k_pos<<<dim3(124), blk, 0, stream>>>(PE2D, PE1D, DWKT, ZB, SQK, TQK,
                                       dwk, sbq, sbk, tbq, tbk);
  k_wprep<<<dim3(1536), blk, 0, stream>>>(sWq, sWk, sWv, sWo, tWq, tWk, tWv, tWo,
                                          cW1, cW2, fW1, fW2, WT);
  // spatial block
  k_ln1<<<gLN, blk, 0, stream>>>(x, g1, b1, PE2D, B1, B2);   // qk->B1, vv->B2
  k_sgemm<5><<<dim3(1, 512), blk, 0, stream>>>(B2, sWvT, 0, sbv, 0, nullptr,
                                               B3, 0, 0);               // VT->B3
  k_sgemm<0><<<dim3(2, 512), blk, 0, stream>>>(B1, sWqT, 65536, SQK, 256, nullptr,
                                               B2, 33554432ull, 256);   // Q->B2,K->B4
  k_sattn2<<<dim3(2048), blk, 0, stream>>>(B2, B4, B3, B1);
  k_sgemm<7><<<dim3(1, 512), blk, 0, stream>>>(B1, sWoT, 0, sbo, 0, x,
                                               XA, 0, 256);             // +x -> XA
  // conv FFN: per half, pair GEMM1 (A read once), 2 dwconv, k_m2 RMW
  k_lnb<<<gLN, blk, 0, stream>>>(XA, g2, b2, B1);
  for (int h = 0; h < 2; ++h) {
    k_sgemm<0><<<dim3(2, 512), blk, 0, stream>>>(B1, cW1T + h * 2 * 65536, 65536,
                                                 cb1 + h * 512, 256, nullptr,
                                                 B2, 33554432ull, 256); // q0->B2,q1->B4
    k_dwconv<<<dim3(Ltok * 32 / 256), blk, 0, stream>>>(B2, DWKT, dwb,
                                                        (h * 2) * 256, 0, H2h);
    k_dwconv<<<dim3(Ltok * 32 / 256), blk, 0, stream>>>(B4, DWKT, dwb,
                                                        (h * 2 + 1) * 256, 256, H2h);
    k_m2<3><<<gM2, blk, 0, stream>>>(H2h, cW2T + h * 512, 1024,
                                     h ? cb2 : ZB, XA, XA, 512);
  }
  // temporal block
  k_ln3b<<<gLN, blk, 0, stream>>>(XA, g3, b3, PE1D, B1, B2, B3);  // base,qt,vt
  k_sgemm<0><<<dim3(1, 512), blk, 0, stream>>>(B3, tWvT, 0, tbv, 0, nullptr,
                                               B4, 0, 256);             // V->B4
  k_sgemm<0><<<dim3(2, 512), blk, 0, stream>>>(B2, tWqT, 65536, TQK, 256, nullptr,
                                               X1, 67108864ull, 256);   // Q->X1,K->B3
  k_tattn2<<<dim3(4096), blk, 0, stream>>>(X1, B3, B4, B2);
  k_sgemm<3><<<dim3(1, 512), blk, 0, stream>>>(B2, tWoT, 0, tbo, 0, B1,
                                               B3, 0, 256);             // +base->B3
  // FFN: LN4 fused into k_ffn (reads pre-LN xt in B3)
  k_ffn<<<dim3(1024), blk, 0, stream>>>(B3, g4, b4, fW1T, fb1, fW2T, fb2,
                                        (float*)d_out);
}

// Round 22
// 756.900 us; speedup vs baseline: 1.0926x; 1.0926x over previous
//
#include <hip/hip_runtime.h>
#include <hip/hip_bf16.h>

typedef unsigned short u16;
typedef unsigned int u32;
typedef __attribute__((ext_vector_type(4))) float f32x4;
typedef __attribute__((ext_vector_type(8))) short s16x8;

// ---- problem dims ----
static constexpr int Nn = 4, Tt = 16, Hh = 32, Ww = 32, Cc = 256;
static constexpr int Ltok = Nn * Tt * Hh * Ww;   // 65536 tokens

// ---- helpers ----
__device__ __forceinline__ float bf2f(u16 v) {
  union { u32 u; float f; } t; t.u = ((u32)v) << 16; return t.f;
}
__device__ __forceinline__ u16 f2bf(float f) {
  union { u32 u; float f; } t; t.f = f;
  return (u16)((t.u + 0x7fffu + ((t.u >> 16) & 1u)) >> 16);  // RNE
}
__device__ __forceinline__ ushort4 pack4(float a, float b, float c, float d) {
  ushort4 r; r.x = f2bf(a); r.y = f2bf(b); r.z = f2bf(c); r.w = f2bf(d); return r;
}
__device__ __forceinline__ float geluf(float x) {
  return 0.5f * x * (1.0f + erff(x * 0.70710678118654752f));
}
__device__ __forceinline__ float wsum(float v) {
#pragma unroll
  for (int o = 32; o > 0; o >>= 1) v += __shfl_xor(v, o, 64);
  return v;
}
__device__ __forceinline__ void ln_stats(float a0, float a1, float a2, float a3,
                                         float& m, float& inv) {
  float s  = wsum(a0 + a1 + a2 + a3);
  float s2 = wsum(a0 * a0 + a1 * a1 + a2 * a2 + a3 * a3);
  m = s * (1.0f / 256.0f);
  float v = s2 * (1.0f / 256.0f) - m * m;
  inv = rsqrtf(v + 1e-5f);
}
__device__ __forceinline__ void gload16(const u16* g, u16* l) {
  __builtin_amdgcn_global_load_lds(
      (const __attribute__((address_space(1))) void*)g,
      (__attribute__((address_space(3))) void*)l, 16, 0, 0);
}

// ---- positional tables + dwk transpose + zero-bias + QK bias concat ----
__global__ __launch_bounds__(256) void k_pos(float* __restrict__ pe2d,
                                             float* __restrict__ pe1d,
                                             float* __restrict__ dwkT,
                                             float* __restrict__ zb,
                                             float* __restrict__ sqk,
                                             float* __restrict__ tqk,
                                             const float* __restrict__ dwk,
                                             const float* __restrict__ sbq,
                                             const float* __restrict__ sbk,
                                             const float* __restrict__ tbq,
                                             const float* __restrict__ tbk) {
  int idx = blockIdx.x * 256 + threadIdx.x;
  if (idx < 16384) {
    int y = idx >> 11, r = idx & 2047, x = r >> 8, c = r & 255;
    float pos; int cc;
    if (c < 128) { pos = (float)(y + 1); cc = c; }
    else         { pos = (float)(x + 1); cc = c - 128; }
    float e = (float)(cc & ~1) * (1.0f / 128.0f);
    float v = pos / powf(10000.0f, e);
    pe2d[idx] = (cc & 1) ? cosf(v) : sinf(v);
  } else if (idx < 20480) {
    int i = idx - 16384;
    int t = i >> 8, c = i & 255;
    float e = (float)(c & ~1) * (1.0f / 256.0f);
    float v = (float)t * powf(10000.0f, -e);
    pe1d[i] = (c & 1) ? cosf(v) : sinf(v);
  } else if (idx < 29696) {
    int i = idx - 20480;
    int c = i & 1023, tap = i >> 10;
    dwkT[tap * 1024 + c] = dwk[c * 9 + tap];
  } else if (idx < 30720) {
    zb[idx - 29696] = 0.0f;
  } else if (idx < 31232) {
    int i = idx - 30720;
    sqk[i] = (i < 256) ? sbq[i] : sbk[i - 256];
  } else if (idx < 31744) {
    int i = idx - 31232;
    tqk[i] = (i < 256) ? tbq[i] : tbk[i - 256];
  }
}

// ---- weight convert+transpose: dst[N][K] bf16 <- src[K][N] f32 ----
__global__ __launch_bounds__(256) void k_wprep(
    const float* __restrict__ s0, const float* __restrict__ s1,
    const float* __restrict__ s2, const float* __restrict__ s3,
    const float* __restrict__ s4, const float* __restrict__ s5,
    const float* __restrict__ s6, const float* __restrict__ s7,
    const float* __restrict__ cW1, const float* __restrict__ cW2,
    const float* __restrict__ fW1, const float* __restrict__ fW2,
    u16* __restrict__ WT) {
  __shared__ float Ls[32][33];
  int b = blockIdx.x;
  const float* src; u16* dst; int Kd, Nd, tb;
  if (b < 512) {
    int seg = b >> 6; tb = b & 63; Kd = 256; Nd = 256;
    const float* tab[8] = {s0, s1, s2, s3, s4, s5, s6, s7};
    src = tab[seg]; dst = WT + seg * 65536;
  } else if (b < 768)  { tb = b - 512;  Kd = 256;  Nd = 1024; src = cW1; dst = WT + 524288; }
  else if (b < 1024)   { tb = b - 768;  Kd = 1024; Nd = 256;  src = cW2; dst = WT + 786432; }
  else if (b < 1280)   { tb = b - 1024; Kd = 256;  Nd = 1024; src = fW1; dst = WT + 1048576; }
  else                 { tb = b - 1280; Kd = 1024; Nd = 256;  src = fW2; dst = WT + 1310720; }
  int nt = Nd >> 5;
  int tk = tb / nt, tn = tb % nt;
  int r = threadIdx.x >> 3, c0 = (threadIdx.x & 7) * 4;
  float4 v = *(const float4*)&src[(size_t)(tk * 32 + r) * Nd + tn * 32 + c0];
  Ls[r][c0] = v.x; Ls[r][c0 + 1] = v.y; Ls[r][c0 + 2] = v.z; Ls[r][c0 + 3] = v.w;
  __syncthreads();
  *(ushort4*)&dst[(size_t)(tn * 32 + r) * Kd + tk * 32 + c0] =
      pack4(Ls[c0][r], Ls[c0 + 1][r], Ls[c0 + 2][r], Ls[c0 + 3][r]);
}

// ---- LN kernels ----
__global__ __launch_bounds__(256) void k_ln1(const float* __restrict__ x,
                                             const float* __restrict__ g,
                                             const float* __restrict__ b,
                                             const float* __restrict__ pe2d,
                                             u16* __restrict__ qk,
                                             u16* __restrict__ vv) {
  int l = blockIdx.x * 4 + (threadIdx.x >> 6);
  int lane = threadIdx.x & 63, c0 = lane * 4;
  int idx = l & 1023, hh = idx >> 5, ww = idx & 31;
  float4 xv = *(const float4*)&x[(size_t)l * Cc + c0];
  float4 pv = *(const float4*)&pe2d[(((hh & 7) << 3) | (ww & 7)) * Cc + c0];
  float q0 = xv.x + pv.x, q1 = xv.y + pv.y, q2 = xv.z + pv.z, q3 = xv.w + pv.w;
  float mx, ix, mq, iq;
  ln_stats(xv.x, xv.y, xv.z, xv.w, mx, ix);
  ln_stats(q0, q1, q2, q3, mq, iq);
  float4 gv = *(const float4*)&g[c0];
  float4 bv = *(const float4*)&b[c0];
  *(ushort4*)&qk[(size_t)l * Cc + c0] =
      pack4((q0 - mq) * iq * gv.x + bv.x, (q1 - mq) * iq * gv.y + bv.y,
            (q2 - mq) * iq * gv.z + bv.z, (q3 - mq) * iq * gv.w + bv.w);
  *(ushort4*)&vv[(size_t)l * Cc + c0] =
      pack4((xv.x - mx) * ix * gv.x + bv.x, (xv.y - mx) * ix * gv.y + bv.y,
            (xv.z - mx) * ix * gv.z + bv.z, (xv.w - mx) * ix * gv.w + bv.w);
}

// bf16-input LN
__global__ __launch_bounds__(256) void k_lnb(const u16* __restrict__ x,
                                             const float* __restrict__ g,
                                             const float* __restrict__ b,
                                             u16* __restrict__ out) {
  int l = blockIdx.x * 4 + (threadIdx.x >> 6);
  int lane = threadIdx.x & 63, c0 = lane * 4;
  ushort4 xv4 = *(const ushort4*)&x[(size_t)l * Cc + c0];
  float x0 = bf2f(xv4.x), x1 = bf2f(xv4.y), x2 = bf2f(xv4.z), x3 = bf2f(xv4.w);
  float m, inv;
  ln_stats(x0, x1, x2, x3, m, inv);
  float4 gv = *(const float4*)&g[c0];
  float4 bv = *(const float4*)&b[c0];
  *(ushort4*)&out[(size_t)l * Cc + c0] =
      pack4((x0 - m) * inv * gv.x + bv.x, (x1 - m) * inv * gv.y + bv.y,
            (x2 - m) * inv * gv.z + bv.z, (x3 - m) * inv * gv.w + bv.w);
}

// LN3 stage, bf16 input
__global__ __launch_bounds__(256) void k_ln3b(const u16* __restrict__ xa,
                                              const float* __restrict__ g,
                                              const float* __restrict__ b,
                                              const float* __restrict__ pe1d,
                                              u16* __restrict__ xt_base,
                                              u16* __restrict__ qt,
                                              u16* __restrict__ vt) {
  int l = blockIdx.x * 4 + (threadIdx.x >> 6);
  int lane = threadIdx.x & 63, c0 = lane * 4;
  ushort4 xv4 = *(const ushort4*)&xa[(size_t)l * Cc + c0];
  float x0 = bf2f(xv4.x), x1 = bf2f(xv4.y), x2 = bf2f(xv4.z), x3 = bf2f(xv4.w);
  float4 gv = *(const float4*)&g[c0];
  float4 bv = *(const float4*)&b[c0];
  float m, inv;
  ln_stats(x0, x1, x2, x3, m, inv);
  float t0 = (x0 - m) * inv * gv.x + bv.x;
  float t1 = (x1 - m) * inv * gv.y + bv.y;
  float t2 = (x2 - m) * inv * gv.z + bv.z;
  float t3 = (x3 - m) * inv * gv.w + bv.w;
  *(ushort4*)&xt_base[(size_t)l * Cc + c0] = pack4(t0, t1, t2, t3);
  float m2, inv2;
  ln_stats(t0, t1, t2, t3, m2, inv2);
  *(ushort4*)&vt[(size_t)l * Cc + c0] =
      pack4((t0 - m2) * inv2 * gv.x + bv.x, (t1 - m2) * inv2 * gv.y + bv.y,
            (t2 - m2) * inv2 * gv.z + bv.z, (t3 - m2) * inv2 * gv.w + bv.w);
  int tt = (l >> 10) & 15;
  float4 pv = *(const float4*)&pe1d[tt * Cc + c0];
  float s0 = t0 + pv.x, s1 = t1 + pv.y, s2 = t2 + pv.z, s3 = t3 + pv.w;
  float m3, inv3;
  ln_stats(s0, s1, s2, s3, m3, inv3);
  *(ushort4*)&qt[(size_t)l * Cc + c0] =
      pack4((s0 - m3) * inv3 * gv.x + bv.x, (s1 - m3) * inv3 * gv.y + bv.y,
            (s2 - m3) * inv3 * gv.z + bv.z, (s3 - m3) * inv3 * gv.w + bv.w);
}

// ---- STREAMING GEMM (tall-skinny), multi-split: grid (splits, 512).
// per-x offsets: WT += bx*wt_stride, bias += bx*bias_stride, out += bx*out_xoff.
// MODE 0: ->bf16 ; 1: gelu->bf16 ; 3: +res(bf16)->bf16 ; 5: ->bf16 transposed
// (coalesced) ; 7: +res(f32)->bf16.
template <int MODE>
__global__ __launch_bounds__(256, 2) void k_sgemm(const u16* __restrict__ A,
                                                  const u16* __restrict__ WT,
                                                  int wt_stride,
                                                  const float* __restrict__ bias,
                                                  int bias_stride,
                                                  const void* __restrict__ res,
                                                  void* __restrict__ out,
                                                  size_t out_xoff, int ldout) {
  __shared__ u16 SMEM[32768];        // A dbuf 2x16KB + scratch 32KB = 64KB
  const int tid = threadIdx.x;
  const int wave = tid >> 6, lane = tid & 63;
  const int fr = lane & 15, fs = lane >> 4;
  const int bx = blockIdx.x;
  const int r0base = blockIdx.y * 128;
  WT += (size_t)bx * wt_stride;
  bias += bx * bias_stride;
  u16* ob = (u16*)out + (size_t)bx * out_xoff;
  s16x8 wreg[4][8];
#pragma unroll
  for (int ni = 0; ni < 4; ++ni)
#pragma unroll
    for (int kt = 0; kt < 8; ++kt)
      wreg[ni][kt] = *(const s16x8*)&WT[(size_t)(wave * 64 + ni * 16 + fr) * 256 +
                                        kt * 32 + fs * 8];
  auto stage = [&](int buf, int r0) {
    u16* Ad = SMEM + buf * 8192;
#pragma unroll
    for (int i = 0; i < 4; ++i) {
      int idx = i * 256 + tid;
      int row = idx >> 5, s = idx & 31;
      gload16(A + (size_t)(r0 + row) * 256 + ((s ^ row) << 3), &Ad[idx * 8]);
    }
  };
  float* sc = (float*)(SMEM + 16384) + wave * 2048;   // per-wave 32x64 f32
  u16* sc2 = SMEM + 16384 + wave * 2048;              // per-wave 64x32 bf16 (MODE 5)
  stage(0, r0base);
  __syncthreads();
#pragma unroll 1
  for (int c = 0; c < 4; ++c) {
    if (c < 3) stage((c + 1) & 1, r0base + (c + 1) * 32);
    const u16* As = SMEM + (c & 1) * 8192;
    f32x4 acc[2][4] = {};
#pragma unroll
    for (int kt = 0; kt < 8; ++kt) {
      s16x8 a0 = *(const s16x8*)&As[(fr * 32 + ((kt * 4 + fs) ^ fr)) * 8];
      s16x8 a1 = *(const s16x8*)&As[((16 + fr) * 32 + ((kt * 4 + fs) ^ (16 + fr))) * 8];
#pragma unroll
      for (int ni = 0; ni < 4; ++ni) {
        acc[0][ni] = __builtin_amdgcn_mfma_f32_16x16x32_bf16(a0, wreg[ni][kt],
                                                             acc[0][ni], 0, 0, 0);
        acc[1][ni] = __builtin_amdgcn_mfma_f32_16x16x32_bf16(a1, wreg[ni][kt],
                                                             acc[1][ni], 0, 0, 0);
      }
    }
    const int r0 = r0base + c * 32;
    if constexpr (MODE == 5) {
      u16* o = (u16*)out;
#pragma unroll
      for (int ni = 0; ni < 4; ++ni) {
        float bv = bias[wave * 64 + ni * 16 + fr];
#pragma unroll
        for (int mi = 0; mi < 2; ++mi)
#pragma unroll
          for (int r = 0; r < 4; ++r) {
            int row = mi * 16 + fs * 4 + r;
            int col = ni * 16 + fr;
            sc2[col * 32 + row] = f2bf(acc[mi][ni][r] + bv);
          }
      }
#pragma unroll
      for (int p = 0; p < 4; ++p) {
        int gcl = p * 16 + (lane >> 2);
        int sub = lane & 3;
        uint4 u = *(const uint4*)&sc2[gcl * 32 + sub * 8];
        int gc = wave * 64 + gcl;
        *(uint4*)&o[(size_t)gc * (size_t)Ltok + r0 + sub * 8] = u;
      }
    } else {
#pragma unroll
      for (int mi = 0; mi < 2; ++mi)
#pragma unroll
        for (int ni = 0; ni < 4; ++ni)
#pragma unroll
          for (int r = 0; r < 4; ++r) {
            int row = mi * 16 + fs * 4 + r;
            int col = ni * 16 + fr;
            sc[row * 64 + (col ^ ((row & 7) << 3))] = acc[mi][ni][r];
          }
#pragma unroll
      for (int p = 0; p < 8; ++p) {
        int row = p * 4 + (lane >> 4);
        int c4 = (lane & 15) * 4;
        f32x4 v4 = *(const f32x4*)&sc[row * 64 + (c4 ^ ((row & 7) << 3))];
        int gr = r0 + row;
        int gc = wave * 64 + c4;
        float4 bv4 = *(const float4*)&bias[gc];
        float v[4] = {v4[0] + bv4.x, v4[1] + bv4.y, v4[2] + bv4.z, v4[3] + bv4.w};
        size_t o = (size_t)gr * (size_t)ldout + gc;
        if constexpr (MODE == 1) {
#pragma unroll
          for (int j = 0; j < 4; ++j) v[j] = geluf(v[j]);
        }
        if constexpr (MODE == 3) {
          ushort4 r4 = *(const ushort4*)&((const u16*)res)[(size_t)gr * 256 + gc];
          v[0] += bf2f(r4.x); v[1] += bf2f(r4.y); v[2] += bf2f(r4.z); v[3] += bf2f(r4.w);
        }
        if constexpr (MODE == 7) {
          float4 r4 = *(const float4*)&((const float*)res)[(size_t)gr * 256 + gc];
          v[0] += r4.x; v[1] += r4.y; v[2] += r4.z; v[3] += r4.w;
        }
        *(ushort4*)&ob[o] = pack4(v[0], v[1], v[2], v[3]);
      }
    }
    __syncthreads();
  }
}

// ---- k_m2: 2-phase dbuf GEMM, BM=128 x BN=128, BK=32 (conv2, K=512) ----
template <int MODE>
__global__ __launch_bounds__(256, 2) void k_m2(const u16* __restrict__ A,
                                               const u16* __restrict__ BT, int ldbt,
                                               const float* __restrict__ bias,
                                               const void* __restrict__ res,
                                               void* __restrict__ out, int K) {
  __shared__ u16 SMEM[16384];
  const int tid = threadIdx.x;
  const int wave = tid >> 6, lane = tid & 63;
  const int fr = lane & 15, fs = lane >> 4;
  const int bid = blockIdx.x;
  const int m0 = (bid >> 1) * 128, n0 = (bid & 1) * 128;
  const int wm = wave >> 1, wn = wave & 1;
  f32x4 acc[4][4] = {};

  auto stage = [&](int buf, int k0) {
    u16* Ad = SMEM + buf * 8192;
    u16* Bd = Ad + 4096;
#pragma unroll
    for (int i = 0; i < 2; ++i) {
      int idx = i * 256 + tid;
      int row = idx >> 2, s = idx & 3;
      gload16(A + (size_t)(m0 + row) * K + k0 + ((s ^ (row & 3)) << 3), &Ad[idx * 8]);
      gload16(BT + (size_t)(n0 + row) * ldbt + k0 + ((s ^ (row & 3)) << 3),
              &Bd[idx * 8]);
    }
  };
  auto compute = [&](int buf) {
    const u16* As = SMEM + buf * 8192;
    const u16* Bs = As + 4096;
    s16x8 af[4], bfr[4];
#pragma unroll
    for (int i = 0; i < 4; ++i) {
      int ra = wm * 64 + i * 16 + fr;
      af[i] = *(const s16x8*)&As[ra * 32 + ((fs ^ (ra & 3)) << 3)];
      int rb = wn * 64 + i * 16 + fr;
      bfr[i] = *(const s16x8*)&Bs[rb * 32 + ((fs ^ (rb & 3)) << 3)];
    }
#pragma unroll
    for (int mi = 0; mi < 4; ++mi)
#pragma unroll
      for (int ni = 0; ni < 4; ++ni)
        acc[mi][ni] = __builtin_amdgcn_mfma_f32_16x16x32_bf16(af[mi], bfr[ni],
                                                              acc[mi][ni], 0, 0, 0);
  };

  stage(0, 0);
  __syncthreads();
  const int nt = K >> 5;
  int cur = 0;
  for (int t = 0; t < nt; ++t) {
    if (t < nt - 1) stage(cur ^ 1, (t + 1) << 5);
    compute(cur);
    __syncthreads();
    cur ^= 1;
  }
  float* Wl = (float*)SMEM + wave * 2048;
#pragma unroll
  for (int nh = 0; nh < 2; ++nh) {
#pragma unroll
    for (int mi = 0; mi < 4; ++mi)
#pragma unroll
      for (int nq = 0; nq < 2; ++nq) {
        int ni = nh * 2 + nq;
#pragma unroll
        for (int r = 0; r < 4; ++r) {
          int row = mi * 16 + fs * 4 + r;
          int col = nq * 16 + fr;
          Wl[row * 32 + (col ^ ((row & 7) << 2))] = acc[mi][ni][r];
        }
      }
#pragma unroll
    for (int p = 0; p < 8; ++p) {
      int row = p * 8 + (lane >> 3);
      int c4 = (lane & 7) * 4;
      f32x4 v4 = *(const f32x4*)&Wl[row * 32 + (c4 ^ ((row & 7) << 2))];
      int gr = m0 + wm * 64 + row;
      int gc = n0 + wn * 64 + nh * 32 + c4;
      float4 bv4 = *(const float4*)&bias[gc];
      float v[4] = {v4[0] + bv4.x, v4[1] + bv4.y, v4[2] + bv4.z, v4[3] + bv4.w};
      size_t o = (size_t)gr * 256 + gc;
      ushort4 r4 = *(const ushort4*)&((const u16*)res)[o];
      v[0] += bf2f(r4.x); v[1] += bf2f(r4.y); v[2] += bf2f(r4.z); v[3] += bf2f(r4.w);
      *(ushort4*)&((u16*)out)[o] = pack4(v[0], v[1], v[2], v[3]);
    }
    __syncthreads();
  }
}

// ---- FUSED LN4+FFN v6b: out[L,256](f32) = 2*(gelu(LN(xt)@W1+b1)@W2+b2)
// 64-row blocks (grid 1024); xt staged once (32KB), LN applied IN LDS;
// 16 hidden-slices of 64 with single H buffer (8KB). launch_bounds(256,3):
// no VGPR cap below ~85 (R21's (256,4) forced 64 VGPR -> scratch spills).
__global__ __launch_bounds__(256, 3) void k_ffn(const u16* __restrict__ X,
                                                const float* __restrict__ g4,
                                                const float* __restrict__ b4,
                                                const u16* __restrict__ W1T,
                                                const float* __restrict__ fb1,
                                                const u16* __restrict__ W2T,
                                                const float* __restrict__ fb2,
                                                float* __restrict__ out) {
  __shared__ u16 SMEM[20480];   // A [64][256] 32KB + H [64][64] 8KB = 40KB
  const int tid = threadIdx.x;
  const int wave = tid >> 6, lane = tid & 63;
  const int fr = lane & 15, fs = lane >> 4;
  const int r0 = blockIdx.x * 64;
  u16* Ald = SMEM;
  u16* Hld = SMEM + 16384;
#pragma unroll
  for (int i = 0; i < 8; ++i) {
    int idx = i * 256 + tid;
    int row = idx >> 5, s = idx & 31;
    gload16(X + (size_t)(r0 + row) * 256 + ((s ^ (row & 7)) << 3), &Ald[idx * 8]);
  }
  __syncthreads();
  // ---- fused LN4 in LDS: thread owns 1/4 row (8 swizzled 16B slots) ----
  {
    const int row = tid >> 2, part = tid & 3;
    float sum = 0.f, sq = 0.f;
#pragma unroll
    for (int s = 0; s < 8; ++s) {
      int slot = part * 8 + s;
      s16x8 v = *(const s16x8*)&Ald[row * 256 + ((slot ^ (row & 7)) << 3)];
#pragma unroll
      for (int j = 0; j < 8; ++j) {
        float f = bf2f((u16)v[j]);
        sum += f; sq += f * f;
      }
    }
    sum += __shfl_xor(sum, 1, 64); sum += __shfl_xor(sum, 2, 64);
    sq  += __shfl_xor(sq, 1, 64);  sq  += __shfl_xor(sq, 2, 64);
    float m = sum * (1.0f / 256.0f);
    float inv = rsqrtf(sq * (1.0f / 256.0f) - m * m + 1e-5f);
#pragma unroll
    for (int s = 0; s < 8; ++s) {
      int slot = part * 8 + s;
      u16* p = &Ald[row * 256 + ((slot ^ (row & 7)) << 3)];
      s16x8 v = *(const s16x8*)p;
      int c0 = slot * 8;
      float4 ga = *(const float4*)&g4[c0];
      float4 gb = *(const float4*)&g4[c0 + 4];
      float4 ba = *(const float4*)&b4[c0];
      float4 bb = *(const float4*)&b4[c0 + 4];
      u16 ov[8];
      ov[0] = f2bf((bf2f((u16)v[0]) - m) * inv * ga.x + ba.x);
      ov[1] = f2bf((bf2f((u16)v[1]) - m) * inv * ga.y + ba.y);
      ov[2] = f2bf((bf2f((u16)v[2]) - m) * inv * ga.z + ba.z);
      ov[3] = f2bf((bf2f((u16)v[3]) - m) * inv * ga.w + ba.w);
      ov[4] = f2bf((bf2f((u16)v[4]) - m) * inv * gb.x + bb.x);
      ov[5] = f2bf((bf2f((u16)v[5]) - m) * inv * gb.y + bb.y);
      ov[6] = f2bf((bf2f((u16)v[6]) - m) * inv * gb.z + bb.z);
      ov[7] = f2bf((bf2f((u16)v[7]) - m) * inv * gb.w + bb.w);
      *(uint4*)p = *(const uint4*)ov;
    }
  }
  __syncthreads();
  f32x4 acc[4][4] = {};
#pragma unroll 1
  for (int j = 0; j < 16; ++j) {
    s16x8 w1f[8];
#pragma unroll
    for (int kt = 0; kt < 8; ++kt)
      w1f[kt] = *(const s16x8*)&W1T[(size_t)(j * 64 + wave * 16 + fr) * 256 +
                                    kt * 32 + fs * 8];
    f32x4 h[4] = {};
#pragma unroll
    for (int kt = 0; kt < 8; ++kt)
#pragma unroll
      for (int mi = 0; mi < 4; ++mi) {
        int row = mi * 16 + fr;
        s16x8 a = *(const s16x8*)&Ald[row * 256 + (((kt * 4 + fs) ^ (row & 7)) << 3)];
        h[mi] = __builtin_amdgcn_mfma_f32_16x16x32_bf16(w1f[kt], a, h[mi], 0, 0, 0);
      }
    float4 b1 = *(const float4*)&fb1[j * 64 + wave * 16 + fs * 4];
    s16x8 w2f[2][4];
#pragma unroll
    for (int kk = 0; kk < 2; ++kk)
#pragma unroll
      for (int nj = 0; nj < 4; ++nj)
        w2f[kk][nj] = *(const s16x8*)&W2T[(size_t)(wave * 64 + nj * 16 + fr) * 1024 +
                                          j * 64 + kk * 32 + fs * 8];
    __syncthreads();   // prev slice's PV reads of Hld are done
#pragma unroll
    for (int mi = 0; mi < 4; ++mi) {
      int tk = mi * 16 + fr;
      int slot = (wave * 2 + (fs >> 1)) ^ (tk & 7);
      *(ushort4*)((char*)Hld + tk * 128 + slot * 16 + (fs & 1) * 8) =
          pack4(geluf(h[mi][0] + b1.x), geluf(h[mi][1] + b1.y),
                geluf(h[mi][2] + b1.z), geluf(h[mi][3] + b1.w));
    }
    __syncthreads();   // H ready
#pragma unroll
    for (int kk = 0; kk < 2; ++kk) {
      s16x8 ha[4];
#pragma unroll
      for (int mi = 0; mi < 4; ++mi) {
        int row = mi * 16 + fr;
        ha[mi] = *(const s16x8*)&Hld[row * 64 + (((kk * 4 + fs) ^ (row & 7)) << 3)];
      }
#pragma unroll
      for (int mi = 0; mi < 4; ++mi)
#pragma unroll
        for (int nj = 0; nj < 4; ++nj)
          acc[mi][nj] = __builtin_amdgcn_mfma_f32_16x16x32_bf16(ha[mi], w2f[kk][nj],
                                                                acc[mi][nj], 0, 0, 0);
    }
  }
  float* Wl = (float*)Ald + wave * 2048;
#pragma unroll
  for (int nh = 0; nh < 2; ++nh) {
#pragma unroll
    for (int mi = 0; mi < 4; ++mi)
#pragma unroll
      for (int nq = 0; nq < 2; ++nq) {
        int ni = nh * 2 + nq;
#pragma unroll
        for (int r = 0; r < 4; ++r) {
          int row = mi * 16 + fs * 4 + r;
          int col = nq * 16 + fr;
          Wl[row * 32 + (col ^ ((row & 7) << 2))] = acc[mi][ni][r];
        }
      }
#pragma unroll
    for (int p = 0; p < 8; ++p) {
      int row = p * 8 + (lane >> 3);
      int c4 = (lane & 7) * 4;
      f32x4 v4 = *(const f32x4*)&Wl[row * 32 + (c4 ^ ((row & 7) << 2))];
      int gr = r0 + row;
      int gc = wave * 64 + nh * 32 + c4;
      float4 bv4 = *(const float4*)&fb2[gc];
      *(float4*)&out[(size_t)gr * 256 + gc] =
          make_float4((v4[0] + bv4.x) * 2.0f, (v4[1] + bv4.y) * 2.0f,
                      (v4[2] + bv4.z) * 2.0f, (v4[3] + bv4.w) * 2.0f);
    }
  }
}

// ---- spatial windowed attention ----
__global__ __launch_bounds__(256) void k_sattn2(const u16* __restrict__ Q,
                                                const u16* __restrict__ Kb,
                                                const u16* __restrict__ VT,
                                                u16* __restrict__ ctx) {
  __shared__ u16 P_lds[4][4096];
  const int tid = threadIdx.x;
  const int wave = tid >> 6, lane = tid & 63;
  const int fr = lane & 15, fs = lane >> 4;
  const int wi = blockIdx.x >> 1;
  const int head = (blockIdx.x & 1) * 4 + wave;
  const int ft = wi >> 4, wy = (wi >> 2) & 3, wx = wi & 3;
  const int base = ft * 1024 + wy * 256 + wx * 8;
  const float scale = 0.17677669529663688f;
  const int ch = head * 32 + fs * 8;
  s16x8 ka[4], qb[4];
#pragma unroll
  for (int t4 = 0; t4 < 4; ++t4) {
    int tok = base + (2 * t4 + (fr >> 3)) * 32 + (fr & 7);
    ka[t4] = *(const s16x8*)&Kb[(size_t)tok * 256 + ch];
    qb[t4] = *(const s16x8*)&Q[(size_t)tok * 256 + ch];
  }
  f32x4 s[4][4] = {};
#pragma unroll
  for (int kt = 0; kt < 4; ++kt)
#pragma unroll
    for (int qt = 0; qt < 4; ++qt)
      s[kt][qt] = __builtin_amdgcn_mfma_f32_16x16x32_bf16(ka[kt], qb[qt], s[kt][qt], 0, 0, 0);
  u16* pw = P_lds[wave];
#pragma unroll
  for (int qt = 0; qt < 4; ++qt) {
    float m = -1e30f;
#pragma unroll
    for (int kt = 0; kt < 4; ++kt)
#pragma unroll
      for (int r = 0; r < 4; ++r) m = fmaxf(m, s[kt][qt][r]);
    m = fmaxf(m, __shfl_xor(m, 16, 64));
    m = fmaxf(m, __shfl_xor(m, 32, 64));
    m *= scale;
    float e[4][4];
    float sum = 0.f;
#pragma unroll
    for (int kt = 0; kt < 4; ++kt)
#pragma unroll
      for (int r = 0; r < 4; ++r) {
        e[kt][r] = __expf(s[kt][qt][r] * scale - m);
        sum += e[kt][r];
      }
    sum += __shfl_xor(sum, 16, 64);
    sum += __shfl_xor(sum, 32, 64);
    float il = 1.0f / sum;
    int q = qt * 16 + fr;
    int rowb = q * 128, sw = (q & 7) << 4;
#pragma unroll
    for (int kt = 0; kt < 4; ++kt)
      *(ushort4*)((char*)pw + ((rowb + kt * 32 + fs * 8) ^ sw)) =
          pack4(e[kt][0] * il, e[kt][1] * il, e[kt][2] * il, e[kt][3] * il);
  }
  f32x4 o[4][2] = {};
#pragma unroll
  for (int ks = 0; ks < 2; ++ks) {
    s16x8 vb[2];
#pragma unroll
    for (int nt = 0; nt < 2; ++nt) {
      int d = head * 32 + nt * 16 + fr;
      int tok = base + (ks * 4 + fs) * 32;
      vb[nt] = *(const s16x8*)&VT[(size_t)d * (size_t)Ltok + tok];
    }
#pragma unroll
    for (int qt = 0; qt < 4; ++qt) {
      int q = qt * 16 + fr;
      s16x8 pa = *(const s16x8*)((char*)pw +
                                 ((q * 128 + ks * 64 + fs * 16) ^ ((q & 7) << 4)));
#pragma unroll
      for (int nt = 0; nt < 2; ++nt)
        o[qt][nt] = __builtin_amdgcn_mfma_f32_16x16x32_bf16(pa, vb[nt], o[qt][nt], 0, 0, 0);
    }
  }
#pragma unroll
  for (int qt = 0; qt < 4; ++qt)
#pragma unroll
    for (int r = 0; r < 4; ++r) {
      int q = qt * 16 + fs * 4 + r;
      int tok = base + (q >> 3) * 32 + (q & 7);
#pragma unroll
      for (int nt = 0; nt < 2; ++nt)
        ctx[(size_t)tok * 256 + head * 32 + nt * 16 + fr] = f2bf(o[qt][nt][r]);
    }
}

// ---- temporal attention ----
__global__ __launch_bounds__(256) void k_tattn2(const u16* __restrict__ Q,
                                                const u16* __restrict__ Kb,
                                                const u16* __restrict__ V,
                                                u16* __restrict__ ctx) {
  __shared__ u16 Vs[16 * 256];
  const int tid = threadIdx.x;
  const int b = blockIdx.x;
  const int n = b >> 10, hw = b & 1023;
  const int tok0 = n * 16384 + hw;
#pragma unroll
  for (int i = 0; i < 2; ++i) {
    int chunk = tid * 2 + i;
    int row = chunk >> 5, c8 = (chunk & 31) * 8;
    *(uint4*)&Vs[row * 256 + c8] =
        *(const uint4*)&V[(size_t)(tok0 + row * 1024) * 256 + c8];
  }
  __syncthreads();
  const int wave = tid >> 6, lane = tid & 63;
  const int fr = lane & 15, fs = lane >> 4;
  const float scale = 0.17677669529663688f;
#pragma unroll
  for (int hg = 0; hg < 2; ++hg) {
    int head = wave + hg * 4;
    int ch = head * 32 + fs * 8;
    size_t go = (size_t)(tok0 + fr * 1024) * 256 + ch;
    s16x8 ka = *(const s16x8*)&Kb[go];
    s16x8 qb = *(const s16x8*)&Q[go];
    f32x4 s = {0.f, 0.f, 0.f, 0.f};
    s = __builtin_amdgcn_mfma_f32_16x16x32_bf16(ka, qb, s, 0, 0, 0);
    float m = fmaxf(fmaxf(s[0], s[1]), fmaxf(s[2], s[3]));
    m = fmaxf(m, __shfl_xor(m, 16, 64));
    m = fmaxf(m, __shfl_xor(m, 32, 64));
    m *= scale;
    float e0 = __expf(s[0] * scale - m), e1 = __expf(s[1] * scale - m);
    float e2 = __expf(s[2] * scale - m), e3 = __expf(s[3] * scale - m);
    float sum = e0 + e1 + e2 + e3;
    sum += __shfl_xor(sum, 16, 64);
    sum += __shfl_xor(sum, 32, 64);
    float il = 1.0f / sum;
    e0 *= il; e1 *= il; e2 *= il; e3 *= il;
    float o[8] = {};
#pragma unroll
    for (int kb = 0; kb < 4; ++kb) {
      int src = kb * 16 + fr;
      float p0 = __shfl(e0, src, 64);
      float p1 = __shfl(e1, src, 64);
      float p2 = __shfl(e2, src, 64);
      float p3 = __shfl(e3, src, 64);
#pragma unroll
      for (int r = 0; r < 4; ++r) {
        float p = r == 0 ? p0 : (r == 1 ? p1 : (r == 2 ? p2 : p3));
        uint4 vv = *(const uint4*)&Vs[(kb * 4 + r) * 256 + ch];
        const u16* vp = (const u16*)&vv;
#pragma unroll
        for (int u = 0; u < 8; ++u) o[u] = fmaf(p, bf2f(vp[u]), o[u]);
      }
    }
    size_t co = (size_t)(tok0 + fr * 1024) * 256 + ch;
    *(ushort4*)&ctx[co] = pack4(o[0], o[1], o[2], o[3]);
    *(ushort4*)&ctx[co + 4] = pack4(o[4], o[5], o[6], o[7]);
  }
}

// ---- depthwise 3x3 conv + bias + GELU on a 256-channel quarter, out stride 512 ----
__global__ __launch_bounds__(256) void k_dwconv(const u16* __restrict__ Hin,
                                                const float* __restrict__ dwkT,
                                                const float* __restrict__ dwb,
                                                int ch0, int oco,
                                                u16* __restrict__ Hout) {
  int flat = blockIdx.x * 256 + threadIdx.x;
  int l = flat >> 5, cg = flat & 31, c0 = cg * 8, tc0 = ch0 + c0;
  int frame = l >> 10, idx = l & 1023, hh = idx >> 5, ww = idx & 31;
  float acc[8];
  *(float4*)&acc[0] = *(const float4*)&dwb[tc0];
  *(float4*)&acc[4] = *(const float4*)&dwb[tc0 + 4];
#pragma unroll
  for (int ky = -1; ky <= 1; ++ky) {
    int h2 = hh + ky;
    if (h2 < 0 || h2 >= 32) continue;
#pragma unroll
    for (int kx = -1; kx <= 1; ++kx) {
      int w2 = ww + kx;
      if (w2 < 0 || w2 >= 32) continue;
      int ln = frame * 1024 + h2 * 32 + w2;
      uint4 hv = *(const uint4*)&Hin[(size_t)ln * 256 + c0];
      const u16* hp = (const u16*)&hv;
      int tap = (ky + 1) * 3 + (kx + 1);
      float wk[8];
      *(float4*)&wk[0] = *(const float4*)&dwkT[tap * 1024 + tc0];
      *(float4*)&wk[4] = *(const float4*)&dwkT[tap * 1024 + tc0 + 4];
#pragma unroll
      for (int u = 0; u < 8; ++u) acc[u] = fmaf(bf2f(hp[u]), wk[u], acc[u]);
    }
  }
  size_t ob = (size_t)l * 512 + oco + c0;
  *(ushort4*)&Hout[ob] = pack4(geluf(acc[0]), geluf(acc[1]), geluf(acc[2]), geluf(acc[3]));
  *(ushort4*)&Hout[ob + 4] = pack4(geluf(acc[4]), geluf(acc[5]), geluf(acc[6]), geluf(acc[7]));
}

extern "C" void kernel_launch(void* const* d_in, const int* in_sizes, int n_in,
                              void* d_out, int out_size, void* d_ws, size_t ws_size,
                              hipStream_t stream) {
  (void)in_sizes; (void)n_in; (void)out_size; (void)ws_size;
  const float* x   = (const float*)d_in[0];
  const float* g1  = (const float*)d_in[1];  const float* b1  = (const float*)d_in[2];
  const float* g2  = (const float*)d_in[3];  const float* b2  = (const float*)d_in[4];
  const float* g3  = (const float*)d_in[5];  const float* b3  = (const float*)d_in[6];
  const float* g4  = (const float*)d_in[7];  const float* b4  = (const float*)d_in[8];
  const float* sWq = (const float*)d_in[9];  const float* sbq = (const float*)d_in[10];
  const float* sWk = (const float*)d_in[11]; const float* sbk = (const float*)d_in[12];
  const float* sWv = (const float*)d_in[13]; const float* sbv = (const float*)d_in[14];
  const float* sWo = (const float*)d_in[15]; const float* sbo = (const float*)d_in[16];
  const float* tWq = (const float*)d_in[17]; const float* tbq = (const float*)d_in[18];
  const float* tWk = (const float*)d_in[19]; const float* tbk = (const float*)d_in[20];
  const float* tWv = (const float*)d_in[21]; const float* tbv = (const float*)d_in[22];
  const float* tWo = (const float*)d_in[23]; const float* tbo = (const float*)d_in[24];
  const float* cW1 = (const float*)d_in[25]; const float* cb1 = (const float*)d_in[26];
  const float* dwk = (const float*)d_in[27]; const float* dwb = (const float*)d_in[28];
  const float* cW2 = (const float*)d_in[29]; const float* cb2 = (const float*)d_in[30];
  const float* fW1 = (const float*)d_in[31]; const float* fb1 = (const float*)d_in[32];
  const float* fW2 = (const float*)d_in[33]; const float* fb2 = (const float*)d_in[34];

  char* ws = (char*)d_ws;
  const size_t MB = 1ull << 20;
  float* PE2D = (float*)(ws);
  float* PE1D = (float*)(ws + (64 << 10));
  float* DWKT = (float*)(ws + (80 << 10));
  float* ZB   = (float*)(ws + (116 << 10));
  float* SQK  = (float*)(ws + (120 << 10));
  float* TQK  = (float*)(ws + (122 << 10));
  u16*   WT   = (u16*)(ws + (128 << 10));
  u16* XA  = (u16*)(ws + 4 * MB);     // bf16 residual [L,256]
  u16* X1  = (u16*)(ws + 4 * MB);     // temporal Q (XA dead by then)
  u16* B1  = (u16*)(ws + 68 * MB);
  u16* B2  = (u16*)(ws + 100 * MB);
  u16* B3  = (u16*)(ws + 132 * MB);
  u16* B4  = (u16*)(ws + 164 * MB);   // peak 196 MB
  u16* H2h = B3;                      // [L,512] conv hidden half

  u16* sWqT = WT;               // +65536 = sWkT (contiguous)
  u16* sWvT = WT + 2 * 65536;   u16* sWoT = WT + 3 * 65536;
  u16* tWqT = WT + 4 * 65536;   // +65536 = tWkT
  u16* tWvT = WT + 6 * 65536;   u16* tWoT = WT + 7 * 65536;
  u16* cW1T = WT + 524288;      u16* cW2T = WT + 786432;
  u16* fW1T = WT + 1048576;     u16* fW2T = WT + 1310720;

  dim3 blk(256);
  dim3 gLN(Ltok / 4);
  dim3 gM2(1024);

  k_pos<<<dim3(124), blk, 0, stream>>>(PE2D, PE1D, DWKT, ZB, SQK, TQK,
                                       dwk, sbq, sbk, tbq, tbk);
  k_wprep<<<dim3(1536), blk, 0, stream>>>(sWq, sWk, sWv, sWo, tWq, tWk, tWv, tWo,
                                          cW1, cW2, fW1, fW2, WT);
  // spatial block
  k_ln1<<<gLN, blk, 0, stream>>>(x, g1, b1, PE2D, B1, B2);   // qk->B1, vv->B2
  k_sgemm<5><<<dim3(1, 512), blk, 0, stream>>>(B2, sWvT, 0, sbv, 0, nullptr,
                                               B3, 0, 0);               // VT->B3
  k_sgemm<0><<<dim3(2, 512), blk, 0, stream>>>(B1, sWqT, 65536, SQK, 256, nullptr,
                                               B2, 33554432ull, 256);   // Q->B2,K->B4
  k_sattn2<<<dim3(2048), blk, 0, stream>>>(B2, B4, B3, B1);
  k_sgemm<7><<<dim3(1, 512), blk, 0, stream>>>(B1, sWoT, 0, sbo, 0, x,
                                               XA, 0, 256);             // +x -> XA
  // conv FFN: per half, pair GEMM1 (A read once), 2 dwconv, k_m2 RMW
  k_lnb<<<gLN, blk, 0, stream>>>(XA, g2, b2, B1);
  for (int h = 0; h < 2; ++h) {
    k_sgemm<0><<<dim3(2, 512), blk, 0, stream>>>(B1, cW1T + h * 2 * 65536, 65536,
                                                 cb1 + h * 512, 256, nullptr,
                                                 B2, 33554432ull, 256); // q0->B2,q1->B4
    k_dwconv<<<dim3(Ltok * 32 / 256), blk, 0, stream>>>(B2, DWKT, dwb,
                                                        (h * 2) * 256, 0, H2h);
    k_dwconv<<<dim3(Ltok * 32 / 256), blk, 0, stream>>>(B4, DWKT, dwb,
                                                        (h * 2 + 1) * 256, 256, H2h);
    k_m2<3><<<gM2, blk, 0, stream>>>(H2h, cW2T + h * 512, 1024,
                                     h ? cb2 : ZB, XA, XA, 512);
  }
  // temporal block
  k_ln3b<<<gLN, blk, 0, stream>>>(XA, g3, b3, PE1D, B1, B2, B3);  // base,qt,vt
  k_sgemm<0><<<dim3(1, 512), blk, 0, stream>>>(B3, tWvT, 0, tbv, 0, nullptr,
                                               B4, 0, 256);             // V->B4
  k_sgemm<0><<<dim3(2, 512), blk, 0, stream>>>(B2, tWqT, 65536, TQK, 256, nullptr,
                                               X1, 67108864ull, 256);   // Q->X1,K->B3
  k_tattn2<<<dim3(4096), blk, 0, stream>>>(X1, B3, B4, B2);
  k_sgemm<3><<<dim3(1, 512), blk, 0, stream>>>(B2, tWoT, 0, tbo, 0, B1,
                                               B3, 0, 256);             // +base->B3
  // FFN: LN4 fused into k_ffn (reads pre-LN xt in B3)
  k_ffn<<<dim3(1024), blk, 0, stream>>>(B3, g4, b4, fW1T, fb1, fW2T, fb2,
                                        (float*)d_out);
}

// Round 23
// 731.786 us; speedup vs baseline: 1.1301x; 1.0343x over previous
//
#include <hip/hip_runtime.h>
#include <hip/hip_bf16.h>

typedef unsigned short u16;
typedef unsigned int u32;
typedef __attribute__((ext_vector_type(4))) float f32x4;
typedef __attribute__((ext_vector_type(8))) short s16x8;

// ---- problem dims ----
static constexpr int Nn = 4, Tt = 16, Hh = 32, Ww = 32, Cc = 256;
static constexpr int Ltok = Nn * Tt * Hh * Ww;   // 65536 tokens

// ---- helpers ----
__device__ __forceinline__ float bf2f(u16 v) {
  union { u32 u; float f; } t; t.u = ((u32)v) << 16; return t.f;
}
__device__ __forceinline__ u16 f2bf(float f) {
  union { u32 u; float f; } t; t.f = f;
  return (u16)((t.u + 0x7fffu + ((t.u >> 16) & 1u)) >> 16);  // RNE
}
__device__ __forceinline__ ushort4 pack4(float a, float b, float c, float d) {
  ushort4 r; r.x = f2bf(a); r.y = f2bf(b); r.z = f2bf(c); r.w = f2bf(d); return r;
}
__device__ __forceinline__ float geluf(float x) {
  return 0.5f * x * (1.0f + erff(x * 0.70710678118654752f));
}
__device__ __forceinline__ float wsum(float v) {
#pragma unroll
  for (int o = 32; o > 0; o >>= 1) v += __shfl_xor(v, o, 64);
  return v;
}
__device__ __forceinline__ void ln_stats(float a0, float a1, float a2, float a3,
                                         float& m, float& inv) {
  float s  = wsum(a0 + a1 + a2 + a3);
  float s2 = wsum(a0 * a0 + a1 * a1 + a2 * a2 + a3 * a3);
  m = s * (1.0f / 256.0f);
  float v = s2 * (1.0f / 256.0f) - m * m;
  inv = rsqrtf(v + 1e-5f);
}
__device__ __forceinline__ void gload16(const u16* g, u16* l) {
  __builtin_amdgcn_global_load_lds(
      (const __attribute__((address_space(1))) void*)g,
      (__attribute__((address_space(3))) void*)l, 16, 0, 0);
}

// ---- positional tables + dwk transpose + zero-bias + QK bias concat ----
__global__ __launch_bounds__(256) void k_pos(float* __restrict__ pe2d,
                                             float* __restrict__ pe1d,
                                             float* __restrict__ dwkT,
                                             float* __restrict__ zb,
                                             float* __restrict__ sqk,
                                             float* __restrict__ tqk,
                                             const float* __restrict__ dwk,
                                             const float* __restrict__ sbq,
                                             const float* __restrict__ sbk,
                                             const float* __restrict__ tbq,
                                             const float* __restrict__ tbk) {
  int idx = blockIdx.x * 256 + threadIdx.x;
  if (idx < 16384) {
    int y = idx >> 11, r = idx & 2047, x = r >> 8, c = r & 255;
    float pos; int cc;
    if (c < 128) { pos = (float)(y + 1); cc = c; }
    else         { pos = (float)(x + 1); cc = c - 128; }
    float e = (float)(cc & ~1) * (1.0f / 128.0f);
    float v = pos / powf(10000.0f, e);
    pe2d[idx] = (cc & 1) ? cosf(v) : sinf(v);
  } else if (idx < 20480) {
    int i = idx - 16384;
    int t = i >> 8, c = i & 255;
    float e = (float)(c & ~1) * (1.0f / 256.0f);
    float v = (float)t * powf(10000.0f, -e);
    pe1d[i] = (c & 1) ? cosf(v) : sinf(v);
  } else if (idx < 29696) {
    int i = idx - 20480;
    int c = i & 1023, tap = i >> 10;
    dwkT[tap * 1024 + c] = dwk[c * 9 + tap];
  } else if (idx < 30720) {
    zb[idx - 29696] = 0.0f;
  } else if (idx < 31232) {
    int i = idx - 30720;
    sqk[i] = (i < 256) ? sbq[i] : sbk[i - 256];
  } else if (idx < 31744) {
    int i = idx - 31232;
    tqk[i] = (i < 256) ? tbq[i] : tbk[i - 256];
  }
}

// ---- weight convert+transpose: dst[N][K] bf16 <- src[K][N] f32 ----
__global__ __launch_bounds__(256) void k_wprep(
    const float* __restrict__ s0, const float* __restrict__ s1,
    const float* __restrict__ s2, const float* __restrict__ s3,
    const float* __restrict__ s4, const float* __restrict__ s5,
    const float* __restrict__ s6, const float* __restrict__ s7,
    const float* __restrict__ cW1, const float* __restrict__ cW2,
    const float* __restrict__ fW1, const float* __restrict__ fW2,
    u16* __restrict__ WT) {
  __shared__ float Ls[32][33];
  int b = blockIdx.x;
  const float* src; u16* dst; int Kd, Nd, tb;
  if (b < 512) {
    int seg = b >> 6; tb = b & 63; Kd = 256; Nd = 256;
    const float* tab[8] = {s0, s1, s2, s3, s4, s5, s6, s7};
    src = tab[seg]; dst = WT + seg * 65536;
  } else if (b < 768)  { tb = b - 512;  Kd = 256;  Nd = 1024; src = cW1; dst = WT + 524288; }
  else if (b < 1024)   { tb = b - 768;  Kd = 1024; Nd = 256;  src = cW2; dst = WT + 786432; }
  else if (b < 1280)   { tb = b - 1024; Kd = 256;  Nd = 1024; src = fW1; dst = WT + 1048576; }
  else                 { tb = b - 1280; Kd = 1024; Nd = 256;  src = fW2; dst = WT + 1310720; }
  int nt = Nd >> 5;
  int tk = tb / nt, tn = tb % nt;
  int r = threadIdx.x >> 3, c0 = (threadIdx.x & 7) * 4;
  float4 v = *(const float4*)&src[(size_t)(tk * 32 + r) * Nd + tn * 32 + c0];
  Ls[r][c0] = v.x; Ls[r][c0 + 1] = v.y; Ls[r][c0 + 2] = v.z; Ls[r][c0 + 3] = v.w;
  __syncthreads();
  *(ushort4*)&dst[(size_t)(tn * 32 + r) * Kd + tk * 32 + c0] =
      pack4(Ls[c0][r], Ls[c0 + 1][r], Ls[c0 + 2][r], Ls[c0 + 3][r]);
}

// ---- LN kernels ----
__global__ __launch_bounds__(256) void k_ln1(const float* __restrict__ x,
                                             const float* __restrict__ g,
                                             const float* __restrict__ b,
                                             const float* __restrict__ pe2d,
                                             u16* __restrict__ qk,
                                             u16* __restrict__ vv) {
  int l = blockIdx.x * 4 + (threadIdx.x >> 6);
  int lane = threadIdx.x & 63, c0 = lane * 4;
  int idx = l & 1023, hh = idx >> 5, ww = idx & 31;
  float4 xv = *(const float4*)&x[(size_t)l * Cc + c0];
  float4 pv = *(const float4*)&pe2d[(((hh & 7) << 3) | (ww & 7)) * Cc + c0];
  float q0 = xv.x + pv.x, q1 = xv.y + pv.y, q2 = xv.z + pv.z, q3 = xv.w + pv.w;
  float mx, ix, mq, iq;
  ln_stats(xv.x, xv.y, xv.z, xv.w, mx, ix);
  ln_stats(q0, q1, q2, q3, mq, iq);
  float4 gv = *(const float4*)&g[c0];
  float4 bv = *(const float4*)&b[c0];
  *(ushort4*)&qk[(size_t)l * Cc + c0] =
      pack4((q0 - mq) * iq * gv.x + bv.x, (q1 - mq) * iq * gv.y + bv.y,
            (q2 - mq) * iq * gv.z + bv.z, (q3 - mq) * iq * gv.w + bv.w);
  *(ushort4*)&vv[(size_t)l * Cc + c0] =
      pack4((xv.x - mx) * ix * gv.x + bv.x, (xv.y - mx) * ix * gv.y + bv.y,
            (xv.z - mx) * ix * gv.z + bv.z, (xv.w - mx) * ix * gv.w + bv.w);
}

// bf16-input LN
__global__ __launch_bounds__(256) void k_lnb(const u16* __restrict__ x,
                                             const float* __restrict__ g,
                                             const float* __restrict__ b,
                                             u16* __restrict__ out) {
  int l = blockIdx.x * 4 + (threadIdx.x >> 6);
  int lane = threadIdx.x & 63, c0 = lane * 4;
  ushort4 xv4 = *(const ushort4*)&x[(size_t)l * Cc + c0];
  float x0 = bf2f(xv4.x), x1 = bf2f(xv4.y), x2 = bf2f(xv4.z), x3 = bf2f(xv4.w);
  float m, inv;
  ln_stats(x0, x1, x2, x3, m, inv);
  float4 gv = *(const float4*)&g[c0];
  float4 bv = *(const float4*)&b[c0];
  *(ushort4*)&out[(size_t)l * Cc + c0] =
      pack4((x0 - m) * inv * gv.x + bv.x, (x1 - m) * inv * gv.y + bv.y,
            (x2 - m) * inv * gv.z + bv.z, (x3 - m) * inv * gv.w + bv.w);
}

// LN3 stage, bf16 input
__global__ __launch_bounds__(256) void k_ln3b(const u16* __restrict__ xa,
                                              const float* __restrict__ g,
                                              const float* __restrict__ b,
                                              const float* __restrict__ pe1d,
                                              u16* __restrict__ xt_base,
                                              u16* __restrict__ qt,
                                              u16* __restrict__ vt) {
  int l = blockIdx.x * 4 + (threadIdx.x >> 6);
  int lane = threadIdx.x & 63, c0 = lane * 4;
  ushort4 xv4 = *(const ushort4*)&xa[(size_t)l * Cc + c0];
  float x0 = bf2f(xv4.x), x1 = bf2f(xv4.y), x2 = bf2f(xv4.z), x3 = bf2f(xv4.w);
  float4 gv = *(const float4*)&g[c0];
  float4 bv = *(const float4*)&b[c0];
  float m, inv;
  ln_stats(x0, x1, x2, x3, m, inv);
  float t0 = (x0 - m) * inv * gv.x + bv.x;
  float t1 = (x1 - m) * inv * gv.y + bv.y;
  float t2 = (x2 - m) * inv * gv.z + bv.z;
  float t3 = (x3 - m) * inv * gv.w + bv.w;
  *(ushort4*)&xt_base[(size_t)l * Cc + c0] = pack4(t0, t1, t2, t3);
  float m2, inv2;
  ln_stats(t0, t1, t2, t3, m2, inv2);
  *(ushort4*)&vt[(size_t)l * Cc + c0] =
      pack4((t0 - m2) * inv2 * gv.x + bv.x, (t1 - m2) * inv2 * gv.y + bv.y,
            (t2 - m2) * inv2 * gv.z + bv.z, (t3 - m2) * inv2 * gv.w + bv.w);
  int tt = (l >> 10) & 15;
  float4 pv = *(const float4*)&pe1d[tt * Cc + c0];
  float s0 = t0 + pv.x, s1 = t1 + pv.y, s2 = t2 + pv.z, s3 = t3 + pv.w;
  float m3, inv3;
  ln_stats(s0, s1, s2, s3, m3, inv3);
  *(ushort4*)&qt[(size_t)l * Cc + c0] =
      pack4((s0 - m3) * inv3 * gv.x + bv.x, (s1 - m3) * inv3 * gv.y + bv.y,
            (s2 - m3) * inv3 * gv.z + bv.z, (s3 - m3) * inv3 * gv.w + bv.w);
}

// ---- STREAMING GEMM (tall-skinny), multi-split: grid (splits, 512).
// per-x offsets: WT += bx*wt_stride, bias += bx*bias_stride, out += bx*out_xoff.
// MODE 0: ->bf16 ; 1: gelu->bf16 ; 3: +res(bf16)->bf16 ; 5: ->bf16 transposed
// (coalesced) ; 7: +res(f32)->bf16.
template <int MODE>
__global__ __launch_bounds__(256, 2) void k_sgemm(const u16* __restrict__ A,
                                                  const u16* __restrict__ WT,
                                                  int wt_stride,
                                                  const float* __restrict__ bias,
                                                  int bias_stride,
                                                  const void* __restrict__ res,
                                                  void* __restrict__ out,
                                                  size_t out_xoff, int ldout) {
  __shared__ u16 SMEM[32768];        // A dbuf 2x16KB + scratch 32KB = 64KB
  const int tid = threadIdx.x;
  const int wave = tid >> 6, lane = tid & 63;
  const int fr = lane & 15, fs = lane >> 4;
  const int bx = blockIdx.x;
  const int r0base = blockIdx.y * 128;
  WT += (size_t)bx * wt_stride;
  bias += bx * bias_stride;
  u16* ob = (u16*)out + (size_t)bx * out_xoff;
  s16x8 wreg[4][8];
#pragma unroll
  for (int ni = 0; ni < 4; ++ni)
#pragma unroll
    for (int kt = 0; kt < 8; ++kt)
      wreg[ni][kt] = *(const s16x8*)&WT[(size_t)(wave * 64 + ni * 16 + fr) * 256 +
                                        kt * 32 + fs * 8];
  auto stage = [&](int buf, int r0) {
    u16* Ad = SMEM + buf * 8192;
#pragma unroll
    for (int i = 0; i < 4; ++i) {
      int idx = i * 256 + tid;
      int row = idx >> 5, s = idx & 31;
      gload16(A + (size_t)(r0 + row) * 256 + ((s ^ row) << 3), &Ad[idx * 8]);
    }
  };
  float* sc = (float*)(SMEM + 16384) + wave * 2048;   // per-wave 32x64 f32
  u16* sc2 = SMEM + 16384 + wave * 2048;              // per-wave 64x32 bf16 (MODE 5)
  stage(0, r0base);
  __syncthreads();
#pragma unroll 1
  for (int c = 0; c < 4; ++c) {
    if (c < 3) stage((c + 1) & 1, r0base + (c + 1) * 32);
    const u16* As = SMEM + (c & 1) * 8192;
    f32x4 acc[2][4] = {};
#pragma unroll
    for (int kt = 0; kt < 8; ++kt) {
      s16x8 a0 = *(const s16x8*)&As[(fr * 32 + ((kt * 4 + fs) ^ fr)) * 8];
      s16x8 a1 = *(const s16x8*)&As[((16 + fr) * 32 + ((kt * 4 + fs) ^ (16 + fr))) * 8];
#pragma unroll
      for (int ni = 0; ni < 4; ++ni) {
        acc[0][ni] = __builtin_amdgcn_mfma_f32_16x16x32_bf16(a0, wreg[ni][kt],
                                                             acc[0][ni], 0, 0, 0);
        acc[1][ni] = __builtin_amdgcn_mfma_f32_16x16x32_bf16(a1, wreg[ni][kt],
                                                             acc[1][ni], 0, 0, 0);
      }
    }
    const int r0 = r0base + c * 32;
    if constexpr (MODE == 5) {
      u16* o = (u16*)out;
#pragma unroll
      for (int ni = 0; ni < 4; ++ni) {
        float bv = bias[wave * 64 + ni * 16 + fr];
#pragma unroll
        for (int mi = 0; mi < 2; ++mi)
#pragma unroll
          for (int r = 0; r < 4; ++r) {
            int row = mi * 16 + fs * 4 + r;
            int col = ni * 16 + fr;
            sc2[col * 32 + row] = f2bf(acc[mi][ni][r] + bv);
          }
      }
#pragma unroll
      for (int p = 0; p < 4; ++p) {
        int gcl = p * 16 + (lane >> 2);
        int sub = lane & 3;
        uint4 u = *(const uint4*)&sc2[gcl * 32 + sub * 8];
        int gc = wave * 64 + gcl;
        *(uint4*)&o[(size_t)gc * (size_t)Ltok + r0 + sub * 8] = u;
      }
    } else {
#pragma unroll
      for (int mi = 0; mi < 2; ++mi)
#pragma unroll
        for (int ni = 0; ni < 4; ++ni)
#pragma unroll
          for (int r = 0; r < 4; ++r) {
            int row = mi * 16 + fs * 4 + r;
            int col = ni * 16 + fr;
            sc[row * 64 + (col ^ ((row & 7) << 3))] = acc[mi][ni][r];
          }
#pragma unroll
      for (int p = 0; p < 8; ++p) {
        int row = p * 4 + (lane >> 4);
        int c4 = (lane & 15) * 4;
        f32x4 v4 = *(const f32x4*)&sc[row * 64 + (c4 ^ ((row & 7) << 3))];
        int gr = r0 + row;
        int gc = wave * 64 + c4;
        float4 bv4 = *(const float4*)&bias[gc];
        float v[4] = {v4[0] + bv4.x, v4[1] + bv4.y, v4[2] + bv4.z, v4[3] + bv4.w};
        size_t o = (size_t)gr * (size_t)ldout + gc;
        if constexpr (MODE == 1) {
#pragma unroll
          for (int j = 0; j < 4; ++j) v[j] = geluf(v[j]);
        }
        if constexpr (MODE == 3) {
          ushort4 r4 = *(const ushort4*)&((const u16*)res)[(size_t)gr * 256 + gc];
          v[0] += bf2f(r4.x); v[1] += bf2f(r4.y); v[2] += bf2f(r4.z); v[3] += bf2f(r4.w);
        }
        if constexpr (MODE == 7) {
          float4 r4 = *(const float4*)&((const float*)res)[(size_t)gr * 256 + gc];
          v[0] += r4.x; v[1] += r4.y; v[2] += r4.z; v[3] += r4.w;
        }
        *(ushort4*)&ob[o] = pack4(v[0], v[1], v[2], v[3]);
      }
    }
    __syncthreads();
  }
}

// ---- k_m2: 2-phase dbuf GEMM, BM=128 x BN=128, BK=32 (conv2, K=512) ----
template <int MODE>
__global__ __launch_bounds__(256, 2) void k_m2(const u16* __restrict__ A,
                                               const u16* __restrict__ BT, int ldbt,
                                               const float* __restrict__ bias,
                                               const void* __restrict__ res,
                                               void* __restrict__ out, int K) {
  __shared__ u16 SMEM[16384];
  const int tid = threadIdx.x;
  const int wave = tid >> 6, lane = tid & 63;
  const int fr = lane & 15, fs = lane >> 4;
  const int bid = blockIdx.x;
  const int m0 = (bid >> 1) * 128, n0 = (bid & 1) * 128;
  const int wm = wave >> 1, wn = wave & 1;
  f32x4 acc[4][4] = {};

  auto stage = [&](int buf, int k0) {
    u16* Ad = SMEM + buf * 8192;
    u16* Bd = Ad + 4096;
#pragma unroll
    for (int i = 0; i < 2; ++i) {
      int idx = i * 256 + tid;
      int row = idx >> 2, s = idx & 3;
      gload16(A + (size_t)(m0 + row) * K + k0 + ((s ^ (row & 3)) << 3), &Ad[idx * 8]);
      gload16(BT + (size_t)(n0 + row) * ldbt + k0 + ((s ^ (row & 3)) << 3),
              &Bd[idx * 8]);
    }
  };
  auto compute = [&](int buf) {
    const u16* As = SMEM + buf * 8192;
    const u16* Bs = As + 4096;
    s16x8 af[4], bfr[4];
#pragma unroll
    for (int i = 0; i < 4; ++i) {
      int ra = wm * 64 + i * 16 + fr;
      af[i] = *(const s16x8*)&As[ra * 32 + ((fs ^ (ra & 3)) << 3)];
      int rb = wn * 64 + i * 16 + fr;
      bfr[i] = *(const s16x8*)&Bs[rb * 32 + ((fs ^ (rb & 3)) << 3)];
    }
#pragma unroll
    for (int mi = 0; mi < 4; ++mi)
#pragma unroll
      for (int ni = 0; ni < 4; ++ni)
        acc[mi][ni] = __builtin_amdgcn_mfma_f32_16x16x32_bf16(af[mi], bfr[ni],
                                                              acc[mi][ni], 0, 0, 0);
  };

  stage(0, 0);
  __syncthreads();
  const int nt = K >> 5;
  int cur = 0;
  for (int t = 0; t < nt; ++t) {
    if (t < nt - 1) stage(cur ^ 1, (t + 1) << 5);
    compute(cur);
    __syncthreads();
    cur ^= 1;
  }
  float* Wl = (float*)SMEM + wave * 2048;
#pragma unroll
  for (int nh = 0; nh < 2; ++nh) {
#pragma unroll
    for (int mi = 0; mi < 4; ++mi)
#pragma unroll
      for (int nq = 0; nq < 2; ++nq) {
        int ni = nh * 2 + nq;
#pragma unroll
        for (int r = 0; r < 4; ++r) {
          int row = mi * 16 + fs * 4 + r;
          int col = nq * 16 + fr;
          Wl[row * 32 + (col ^ ((row & 7) << 2))] = acc[mi][ni][r];
        }
      }
#pragma unroll
    for (int p = 0; p < 8; ++p) {
      int row = p * 8 + (lane >> 3);
      int c4 = (lane & 7) * 4;
      f32x4 v4 = *(const f32x4*)&Wl[row * 32 + (c4 ^ ((row & 7) << 2))];
      int gr = m0 + wm * 64 + row;
      int gc = n0 + wn * 64 + nh * 32 + c4;
      float4 bv4 = *(const float4*)&bias[gc];
      float v[4] = {v4[0] + bv4.x, v4[1] + bv4.y, v4[2] + bv4.z, v4[3] + bv4.w};
      size_t o = (size_t)gr * 256 + gc;
      ushort4 r4 = *(const ushort4*)&((const u16*)res)[o];
      v[0] += bf2f(r4.x); v[1] += bf2f(r4.y); v[2] += bf2f(r4.z); v[3] += bf2f(r4.w);
      *(ushort4*)&((u16*)out)[o] = pack4(v[0], v[1], v[2], v[3]);
    }
    __syncthreads();
  }
}

// ---- FUSED FFN (R19 body + s_setprio): out[L,256](f32) = 2*(gelu(A@W1+b1)@W2+b2)
// 64-row blocks (grid 1024); A staged once (32KB); 16 hidden-slices of 64.
__global__ __launch_bounds__(256, 3) void k_ffn(const u16* __restrict__ A,
                                                const u16* __restrict__ W1T,
                                                const float* __restrict__ fb1,
                                                const u16* __restrict__ W2T,
                                                const float* __restrict__ fb2,
                                                float* __restrict__ out) {
  __shared__ u16 SMEM[20480];   // A [64][256] 32KB + H [64][64] 8KB
  const int tid = threadIdx.x;
  const int wave = tid >> 6, lane = tid & 63;
  const int fr = lane & 15, fs = lane >> 4;
  const int r0 = blockIdx.x * 64;
  u16* Ald = SMEM;
  u16* Hld = SMEM + 16384;
#pragma unroll
  for (int i = 0; i < 8; ++i) {
    int idx = i * 256 + tid;
    int row = idx >> 5, s = idx & 31;
    gload16(A + (size_t)(r0 + row) * 256 + ((s ^ (row & 7)) << 3), &Ald[idx * 8]);
  }
  __syncthreads();
  f32x4 acc[4][4] = {};
#pragma unroll 1
  for (int j = 0; j < 16; ++j) {
    s16x8 w1f[8];
#pragma unroll
    for (int kt = 0; kt < 8; ++kt)
      w1f[kt] = *(const s16x8*)&W1T[(size_t)(j * 64 + wave * 16 + fr) * 256 +
                                    kt * 32 + fs * 8];
    f32x4 h[4] = {};
    __builtin_amdgcn_s_setprio(1);
#pragma unroll
    for (int kt = 0; kt < 8; ++kt)
#pragma unroll
      for (int mi = 0; mi < 4; ++mi) {
        int row = mi * 16 + fr;
        s16x8 a = *(const s16x8*)&Ald[row * 256 + (((kt * 4 + fs) ^ (row & 7)) << 3)];
        h[mi] = __builtin_amdgcn_mfma_f32_16x16x32_bf16(w1f[kt], a, h[mi], 0, 0, 0);
      }
    __builtin_amdgcn_s_setprio(0);
    float4 b1 = *(const float4*)&fb1[j * 64 + wave * 16 + fs * 4];
    s16x8 w2f[2][4];
#pragma unroll
    for (int kk = 0; kk < 2; ++kk)
#pragma unroll
      for (int nj = 0; nj < 4; ++nj)
        w2f[kk][nj] = *(const s16x8*)&W2T[(size_t)(wave * 64 + nj * 16 + fr) * 1024 +
                                          j * 64 + kk * 32 + fs * 8];
    __syncthreads();   // prev slice's PV reads of Hld are done
#pragma unroll
    for (int mi = 0; mi < 4; ++mi) {
      int tk = mi * 16 + fr;
      int slot = (wave * 2 + (fs >> 1)) ^ (tk & 7);
      *(ushort4*)((char*)Hld + tk * 128 + slot * 16 + (fs & 1) * 8) =
          pack4(geluf(h[mi][0] + b1.x), geluf(h[mi][1] + b1.y),
                geluf(h[mi][2] + b1.z), geluf(h[mi][3] + b1.w));
    }
    __syncthreads();   // H ready
    __builtin_amdgcn_s_setprio(1);
#pragma unroll
    for (int kk = 0; kk < 2; ++kk) {
      s16x8 ha[4];
#pragma unroll
      for (int mi = 0; mi < 4; ++mi) {
        int row = mi * 16 + fr;
        ha[mi] = *(const s16x8*)&Hld[row * 64 + (((kk * 4 + fs) ^ (row & 7)) << 3)];
      }
#pragma unroll
      for (int mi = 0; mi < 4; ++mi)
#pragma unroll
        for (int nj = 0; nj < 4; ++nj)
          acc[mi][nj] = __builtin_amdgcn_mfma_f32_16x16x32_bf16(ha[mi], w2f[kk][nj],
                                                                acc[mi][nj], 0, 0, 0);
    }
    __builtin_amdgcn_s_setprio(0);
  }
  float* Wl = (float*)Ald + wave * 2048;
#pragma unroll
  for (int nh = 0; nh < 2; ++nh) {
#pragma unroll
    for (int mi = 0; mi < 4; ++mi)
#pragma unroll
      for (int nq = 0; nq < 2; ++nq) {
        int ni = nh * 2 + nq;
#pragma unroll
        for (int r = 0; r < 4; ++r) {
          int row = mi * 16 + fs * 4 + r;
          int col = nq * 16 + fr;
          Wl[row * 32 + (col ^ ((row & 7) << 2))] = acc[mi][ni][r];
        }
      }
#pragma unroll
    for (int p = 0; p < 8; ++p) {
      int row = p * 8 + (lane >> 3);
      int c4 = (lane & 7) * 4;
      f32x4 v4 = *(const f32x4*)&Wl[row * 32 + (c4 ^ ((row & 7) << 2))];
      int gr = r0 + row;
      int gc = wave * 64 + nh * 32 + c4;
      float4 bv4 = *(const float4*)&fb2[gc];
      *(float4*)&out[(size_t)gr * 256 + gc] =
          make_float4((v4[0] + bv4.x) * 2.0f, (v4[1] + bv4.y) * 2.0f,
                      (v4[2] + bv4.z) * 2.0f, (v4[3] + bv4.w) * 2.0f);
    }
  }
}

// ---- spatial windowed attention ----
__global__ __launch_bounds__(256) void k_sattn2(const u16* __restrict__ Q,
                                                const u16* __restrict__ Kb,
                                                const u16* __restrict__ VT,
                                                u16* __restrict__ ctx) {
  __shared__ u16 P_lds[4][4096];
  const int tid = threadIdx.x;
  const int wave = tid >> 6, lane = tid & 63;
  const int fr = lane & 15, fs = lane >> 4;
  const int wi = blockIdx.x >> 1;
  const int head = (blockIdx.x & 1) * 4 + wave;
  const int ft = wi >> 4, wy = (wi >> 2) & 3, wx = wi & 3;
  const int base = ft * 1024 + wy * 256 + wx * 8;
  const float scale = 0.17677669529663688f;
  const int ch = head * 32 + fs * 8;
  s16x8 ka[4], qb[4];
#pragma unroll
  for (int t4 = 0; t4 < 4; ++t4) {
    int tok = base + (2 * t4 + (fr >> 3)) * 32 + (fr & 7);
    ka[t4] = *(const s16x8*)&Kb[(size_t)tok * 256 + ch];
    qb[t4] = *(const s16x8*)&Q[(size_t)tok * 256 + ch];
  }
  f32x4 s[4][4] = {};
#pragma unroll
  for (int kt = 0; kt < 4; ++kt)
#pragma unroll
    for (int qt = 0; qt < 4; ++qt)
      s[kt][qt] = __builtin_amdgcn_mfma_f32_16x16x32_bf16(ka[kt], qb[qt], s[kt][qt], 0, 0, 0);
  u16* pw = P_lds[wave];
#pragma unroll
  for (int qt = 0; qt < 4; ++qt) {
    float m = -1e30f;
#pragma unroll
    for (int kt = 0; kt < 4; ++kt)
#pragma unroll
      for (int r = 0; r < 4; ++r) m = fmaxf(m, s[kt][qt][r]);
    m = fmaxf(m, __shfl_xor(m, 16, 64));
    m = fmaxf(m, __shfl_xor(m, 32, 64));
    m *= scale;
    float e[4][4];
    float sum = 0.f;
#pragma unroll
    for (int kt = 0; kt < 4; ++kt)
#pragma unroll
      for (int r = 0; r < 4; ++r) {
        e[kt][r] = __expf(s[kt][qt][r] * scale - m);
        sum += e[kt][r];
      }
    sum += __shfl_xor(sum, 16, 64);
    sum += __shfl_xor(sum, 32, 64);
    float il = 1.0f / sum;
    int q = qt * 16 + fr;
    int rowb = q * 128, sw = (q & 7) << 4;
#pragma unroll
    for (int kt = 0; kt < 4; ++kt)
      *(ushort4*)((char*)pw + ((rowb + kt * 32 + fs * 8) ^ sw)) =
          pack4(e[kt][0] * il, e[kt][1] * il, e[kt][2] * il, e[kt][3] * il);
  }
  f32x4 o[4][2] = {};
#pragma unroll
  for (int ks = 0; ks < 2; ++ks) {
    s16x8 vb[2];
#pragma unroll
    for (int nt = 0; nt < 2; ++nt) {
      int d = head * 32 + nt * 16 + fr;
      int tok = base + (ks * 4 + fs) * 32;
      vb[nt] = *(const s16x8*)&VT[(size_t)d * (size_t)Ltok + tok];
    }
#pragma unroll
    for (int qt = 0; qt < 4; ++qt) {
      int q = qt * 16 + fr;
      s16x8 pa = *(const s16x8*)((char*)pw +
                                 ((q * 128 + ks * 64 + fs * 16) ^ ((q & 7) << 4)));
#pragma unroll
      for (int nt = 0; nt < 2; ++nt)
        o[qt][nt] = __builtin_amdgcn_mfma_f32_16x16x32_bf16(pa, vb[nt], o[qt][nt], 0, 0, 0);
    }
  }
#pragma unroll
  for (int qt = 0; qt < 4; ++qt)
#pragma unroll
    for (int r = 0; r < 4; ++r) {
      int q = qt * 16 + fs * 4 + r;
      int tok = base + (q >> 3) * 32 + (q & 7);
#pragma unroll
      for (int nt = 0; nt < 2; ++nt)
        ctx[(size_t)tok * 256 + head * 32 + nt * 16 + fr] = f2bf(o[qt][nt][r]);
    }
}

// ---- temporal attention ----
__global__ __launch_bounds__(256) void k_tattn2(const u16* __restrict__ Q,
                                                const u16* __restrict__ Kb,
                                                const u16* __restrict__ V,
                                                u16* __restrict__ ctx) {
  __shared__ u16 Vs[16 * 256];
  const int tid = threadIdx.x;
  const int b = blockIdx.x;
  const int n = b >> 10, hw = b & 1023;
  const int tok0 = n * 16384 + hw;
#pragma unroll
  for (int i = 0; i < 2; ++i) {
    int chunk = tid * 2 + i;
    int row = chunk >> 5, c8 = (chunk & 31) * 8;
    *(uint4*)&Vs[row * 256 + c8] =
        *(const uint4*)&V[(size_t)(tok0 + row * 1024) * 256 + c8];
  }
  __syncthreads();
  const int wave = tid >> 6, lane = tid & 63;
  const int fr = lane & 15, fs = lane >> 4;
  const float scale = 0.17677669529663688f;
#pragma unroll
  for (int hg = 0; hg < 2; ++hg) {
    int head = wave + hg * 4;
    int ch = head * 32 + fs * 8;
    size_t go = (size_t)(tok0 + fr * 1024) * 256 + ch;
    s16x8 ka = *(const s16x8*)&Kb[go];
    s16x8 qb = *(const s16x8*)&Q[go];
    f32x4 s = {0.f, 0.f, 0.f, 0.f};
    s = __builtin_amdgcn_mfma_f32_16x16x32_bf16(ka, qb, s, 0, 0, 0);
    float m = fmaxf(fmaxf(s[0], s[1]), fmaxf(s[2], s[3]));
    m = fmaxf(m, __shfl_xor(m, 16, 64));
    m = fmaxf(m, __shfl_xor(m, 32, 64));
    m *= scale;
    float e0 = __expf(s[0] * scale - m), e1 = __expf(s[1] * scale - m);
    float e2 = __expf(s[2] * scale - m), e3 = __expf(s[3] * scale - m);
    float sum = e0 + e1 + e2 + e3;
    sum += __shfl_xor(sum, 16, 64);
    sum += __shfl_xor(sum, 32, 64);
    float il = 1.0f / sum;
    e0 *= il; e1 *= il; e2 *= il; e3 *= il;
    float o[8] = {};
#pragma unroll
    for (int kb = 0; kb < 4; ++kb) {
      int src = kb * 16 + fr;
      float p0 = __shfl(e0, src, 64);
      float p1 = __shfl(e1, src, 64);
      float p2 = __shfl(e2, src, 64);
      float p3 = __shfl(e3, src, 64);
#pragma unroll
      for (int r = 0; r < 4; ++r) {
        float p = r == 0 ? p0 : (r == 1 ? p1 : (r == 2 ? p2 : p3));
        uint4 vv = *(const uint4*)&Vs[(kb * 4 + r) * 256 + ch];
        const u16* vp = (const u16*)&vv;
#pragma unroll
        for (int u = 0; u < 8; ++u) o[u] = fmaf(p, bf2f(vp[u]), o[u]);
      }
    }
    size_t co = (size_t)(tok0 + fr * 1024) * 256 + ch;
    *(ushort4*)&ctx[co] = pack4(o[0], o[1], o[2], o[3]);
    *(ushort4*)&ctx[co + 4] = pack4(o[4], o[5], o[6], o[7]);
  }
}

// ---- depthwise 3x3 conv + bias + GELU on a 256-channel quarter, out stride 512 ----
__global__ __launch_bounds__(256) void k_dwconv(const u16* __restrict__ Hin,
                                                const float* __restrict__ dwkT,
                                                const float* __restrict__ dwb,
                                                int ch0, int oco,
                                                u16* __restrict__ Hout) {
  int flat = blockIdx.x * 256 + threadIdx.x;
  int l = flat >> 5, cg = flat & 31, c0 = cg * 8, tc0 = ch0 + c0;
  int frame = l >> 10, idx = l & 1023, hh = idx >> 5, ww = idx & 31;
  float acc[8];
  *(float4*)&acc[0] = *(const float4*)&dwb[tc0];
  *(float4*)&acc[4] = *(const float4*)&dwb[tc0 + 4];
#pragma unroll
  for (int ky = -1; ky <= 1; ++ky) {
    int h2 = hh + ky;
    if (h2 < 0 || h2 >= 32) continue;
#pragma unroll
    for (int kx = -1; kx <= 1; ++kx) {
      int w2 = ww + kx;
      if (w2 < 0 || w2 >= 32) continue;
      int ln = frame * 1024 + h2 * 32 + w2;
      uint4 hv = *(const uint4*)&Hin[(size_t)ln * 256 + c0];
      const u16* hp = (const u16*)&hv;
      int tap = (ky + 1) * 3 + (kx + 1);
      float wk[8];
      *(float4*)&wk[0] = *(const float4*)&dwkT[tap * 1024 + tc0];
      *(float4*)&wk[4] = *(const float4*)&dwkT[tap * 1024 + tc0 + 4];
#pragma unroll
      for (int u = 0; u < 8; ++u) acc[u] = fmaf(bf2f(hp[u]), wk[u], acc[u]);
    }
  }
  size_t ob = (size_t)l * 512 + oco + c0;
  *(ushort4*)&Hout[ob] = pack4(geluf(acc[0]), geluf(acc[1]), geluf(acc[2]), geluf(acc[3]));
  *(ushort4*)&Hout[ob + 4] = pack4(geluf(acc[4]), geluf(acc[5]), geluf(acc[6]), geluf(acc[7]));
}

extern "C" void kernel_launch(void* const* d_in, const int* in_sizes, int n_in,
                              void* d_out, int out_size, void* d_ws, size_t ws_size,
                              hipStream_t stream) {
  (void)in_sizes; (void)n_in; (void)out_size; (void)ws_size;
  const float* x   = (const float*)d_in[0];
  const float* g1  = (const float*)d_in[1];  const float* b1  = (const float*)d_in[2];
  const float* g2  = (const float*)d_in[3];  const float* b2  = (const float*)d_in[4];
  const float* g3  = (const float*)d_in[5];  const float* b3  = (const float*)d_in[6];
  const float* g4  = (const float*)d_in[7];  const float* b4  = (const float*)d_in[8];
  const float* sWq = (const float*)d_in[9];  const float* sbq = (const float*)d_in[10];
  const float* sWk = (const float*)d_in[11]; const float* sbk = (const float*)d_in[12];
  const float* sWv = (const float*)d_in[13]; const float* sbv = (const float*)d_in[14];
  const float* sWo = (const float*)d_in[15]; const float* sbo = (const float*)d_in[16];
  const float* tWq = (const float*)d_in[17]; const float* tbq = (const float*)d_in[18];
  const float* tWk = (const float*)d_in[19]; const float* tbk = (const float*)d_in[20];
  const float* tWv = (const float*)d_in[21]; const float* tbv = (const float*)d_in[22];
  const float* tWo = (const float*)d_in[23]; const float* tbo = (const float*)d_in[24];
  const float* cW1 = (const float*)d_in[25]; const float* cb1 = (const float*)d_in[26];
  const float* dwk = (const float*)d_in[27]; const float* dwb = (const float*)d_in[28];
  const float* cW2 = (const float*)d_in[29]; const float* cb2 = (const float*)d_in[30];
  const float* fW1 = (const float*)d_in[31]; const float* fb1 = (const float*)d_in[32];
  const float* fW2 = (const float*)d_in[33]; const float* fb2 = (const float*)d_in[34];

  char* ws = (char*)d_ws;
  const size_t MB = 1ull << 20;
  float* PE2D = (float*)(ws);
  float* PE1D = (float*)(ws + (64 << 10));
  float* DWKT = (float*)(ws + (80 << 10));
  float* ZB   = (float*)(ws + (116 << 10));
  float* SQK  = (float*)(ws + (120 << 10));
  float* TQK  = (float*)(ws + (122 << 10));
  u16*   WT   = (u16*)(ws + (128 << 10));
  u16* XA  = (u16*)(ws + 4 * MB);     // bf16 residual [L,256]
  u16* X1  = (u16*)(ws + 4 * MB);     // temporal Q (XA dead by then)
  u16* Q0  = (u16*)(ws + 36 * MB);    // conv GEMM1 q-even output (dead gap)
  u16* B1  = (u16*)(ws + 68 * MB);
  u16* B2  = (u16*)(ws + 100 * MB);
  u16* B3  = (u16*)(ws + 132 * MB);
  u16* B4  = (u16*)(ws + 164 * MB);   // peak 196 MB
  u16* H2h = B3;                      // [L,512] conv hidden half (132-196MB)

  u16* sWqT = WT;               // +65536 = sWkT (contiguous)
  u16* sWvT = WT + 2 * 65536;   u16* sWoT = WT + 3 * 65536;
  u16* tWqT = WT + 4 * 65536;   // +65536 = tWkT
  u16* tWvT = WT + 6 * 65536;   u16* tWoT = WT + 7 * 65536;
  u16* cW1T = WT + 524288;      u16* cW2T = WT + 786432;
  u16* fW1T = WT + 1048576;     u16* fW2T = WT + 1310720;

  dim3 blk(256);
  dim3 gLN(Ltok / 4);
  dim3 gM2(1024);

  k_pos<<<dim3(124), blk, 0, stream>>>(PE2D, PE1D, DWKT, ZB, SQK, TQK,
                                       dwk, sbq, sbk, tbq, tbk);
  k_wprep<<<dim3(1536), blk, 0, stream>>>(sWq, sWk, sWv, sWo, tWq, tWk, tWv, tWo,
                                          cW1, cW2, fW1, fW2, WT);
  // spatial block
  k_ln1<<<gLN, blk, 0, stream>>>(x, g1, b1, PE2D, B1, B2);   // qk->B1, vv->B2
  k_sgemm<5><<<dim3(1, 512), blk, 0, stream>>>(B2, sWvT, 0, sbv, 0, nullptr,
                                               B3, 0, 0);               // VT->B3
  k_sgemm<0><<<dim3(2, 512), blk, 0, stream>>>(B1, sWqT, 65536, SQK, 256, nullptr,
                                               B2, 33554432ull, 256);   // Q->B2,K->B4
  k_sattn2<<<dim3(2048), blk, 0, stream>>>(B2, B4, B3, B1);
  k_sgemm<7><<<dim3(1, 512), blk, 0, stream>>>(B1, sWoT, 0, sbo, 0, x,
                                               XA, 0, 256);             // +x -> XA
  // conv FFN: per half, pair GEMM1 (A read once) -> Q0/B2 (no H2h overlap),
  // 2 dwconv, k_m2 RMW.  (H2h=B3 spans 132-196MB; Q0/B2 sit at 36/100MB.)
  k_lnb<<<gLN, blk, 0, stream>>>(XA, g2, b2, B1);
  for (int h = 0; h < 2; ++h) {
    k_sgemm<0><<<dim3(2, 512), blk, 0, stream>>>(B1, cW1T + h * 2 * 65536, 65536,
                                                 cb1 + h * 512, 256, nullptr,
                                                 Q0, 33554432ull, 256); // q0->Q0,q1->B2
    k_dwconv<<<dim3(Ltok * 32 / 256), blk, 0, stream>>>(Q0, DWKT, dwb,
                                                        (h * 2) * 256, 0, H2h);
    k_dwconv<<<dim3(Ltok * 32 / 256), blk, 0, stream>>>(B2, DWKT, dwb,
                                                        (h * 2 + 1) * 256, 256, H2h);
    k_m2<3><<<gM2, blk, 0, stream>>>(H2h, cW2T + h * 512, 1024,
                                     h ? cb2 : ZB, XA, XA, 512);
  }
  // temporal block
  k_ln3b<<<gLN, blk, 0, stream>>>(XA, g3, b3, PE1D, B1, B2, B3);  // base,qt,vt
  k_sgemm<0><<<dim3(1, 512), blk, 0, stream>>>(B3, tWvT, 0, tbv, 0, nullptr,
                                               B4, 0, 256);             // V->B4
  k_sgemm<0><<<dim3(2, 512), blk, 0, stream>>>(B2, tWqT, 65536, TQK, 256, nullptr,
                                               X1, 67108864ull, 256);   // Q->X1,K->B3
  k_tattn2<<<dim3(4096), blk, 0, stream>>>(X1, B3, B4, B2);
  k_sgemm<3><<<dim3(1, 512), blk, 0, stream>>>(B2, tWoT, 0, tbo, 0, B1,
                                               B3, 0, 256);             // +base->B3
  // FFN (fused)
  k_lnb<<<gLN, blk, 0, stream>>>(B3, g4, b4, B4);
  k_ffn<<<dim3(1024), blk, 0, stream>>>(B4, fW1T, fb1, fW2T, fb2, (float*)d_out);
}